// Round 16
// baseline (141.565 us; speedup 1.0000x reference)
//
#include <hip/hip_runtime.h>
#include <hip/hip_bf16.h>
#include <cmath>

#define DDIM 128
#define NPTS 3136   // 56*56
#define NCHUNK 196  // NPTS/16
#define BATCH 16
#define PROT 2000
#define PPAD 2048   // 16 tiles * 128

typedef __attribute__((ext_vector_type(8))) short bf16x8;
typedef __attribute__((ext_vector_type(4))) float f32x4;
typedef __attribute__((ext_vector_type(4))) unsigned int u32x4;

// ---- workspace layout (float/u32 slot indices) ----
#define WS_X2   0                      // 50176
#define WS_K1   50176                  // 262144 (16 b x 8 pieces x 2048)
#define WS_K2   312320                 // 262144
#define WS_PT   574464                 // 131072 slots (= 262144 shorts, 2048x128)
#define WS_XT   705536                 // 3211264 slots (= 16*196*4096 bytes)
#define WS_XFT  3916800                // 6422528 (16*3136*128 f32)
#define WS_MID  ((size_t)3916800 * 4)
#define WS_BIG  ((size_t)10339328 * 4)

// ---------------- bf16 helpers ----------------
__device__ inline unsigned short bf16rn(float a) {
    unsigned u = __float_as_uint(a);
    unsigned r = u + 0x7FFFu + ((u >> 16) & 1u);
    return (unsigned short)(r >> 16);
}

__device__ __forceinline__ void gload_lds16(const void* g, void* l) {
    __builtin_amdgcn_global_load_lds(
        (const __attribute__((address_space(1))) void*)g,
        (__attribute__((address_space(3))) void*)l, 16, 0, 0);
}
__device__ __forceinline__ void gload_lds4(const void* g, void* l) {
    __builtin_amdgcn_global_load_lds(
        (const __attribute__((address_space(1))) void*)g,
        (__attribute__((address_space(3))) void*)l, 4, 0, 0);
}

// ---------------- fused pre-pass (unchanged from r14/r15, proven) ----------------
__global__ __launch_bounds__(256)
void pp_fused(const float* __restrict__ x, const float* __restrict__ proto,
              unsigned short* __restrict__ xt, unsigned short* __restrict__ pt,
              float* __restrict__ x2, float* __restrict__ xfT) {
    int tid = threadIdx.x;
    if (blockIdx.x == 49) {               // prototype part: 8 blocks x 256 = 2048
        int by = blockIdx.y;
        if (by >= 8) return;
        int p = by * 256 + tid;           // 0..2047
        int ps = min(p, PROT - 1);
        const float* src = proto + (size_t)ps * DDIM;
        unsigned short* dst = pt + (size_t)p * 128;
        for (int j = 0; j < DDIM; ++j) dst[j] = bf16rn(src[j]);
        return;
    }
    __shared__ float xs[DDIM][64];
    int b = blockIdx.y;
    int n0 = blockIdx.x * 64;
    {
        int r = tid >> 4, c = tid & 15;
        #pragma unroll
        for (int it = 0; it < 8; ++it) {
            int row = it * 16 + r;
            f32x4 v = *(const f32x4*)(x + ((size_t)(b * DDIM + row)) * NPTS + n0 + c * 4);
            *(f32x4*)(&xs[row][c * 4]) = v;
        }
    }
    __syncthreads();
    if (tid < 64) {
        float s = 0.f;
        #pragma unroll 8
        for (int d = 0; d < DDIM; ++d) { float v = xs[d][tid]; s = fmaf(v, v, s); }
        x2[b * NPTS + n0 + tid] = (s + 512.0f) * 512.0f;
    }
    int n = tid & 63, kk = tid >> 6;
    int nl = n & 15, ci = (n0 + n) >> 4;
    unsigned int hw[16];
    #pragma unroll
    for (int j = 0; j < 16; ++j) {
        unsigned short h0 = bf16rn(xs[kk * 32 + 2 * j][n]);
        unsigned short h1 = bf16rn(xs[kk * 32 + 2 * j + 1][n]);
        hw[j] = (unsigned)h0 | ((unsigned)h1 << 16);
    }
    char* cb = (char*)xt + ((size_t)b * NCHUNK + ci) * 4096;
    #pragma unroll
    for (int g = 0; g < 4; ++g)
        *(u32x4*)(cb + kk * 1024 + g * 256 + nl * 16) = *(u32x4*)(&hw[g * 4]);
    if (xfT) {
        float* fo = xfT + ((size_t)b * NPTS + n0 + n) * DDIM + kk * 32;
        #pragma unroll
        for (int g = 0; g < 8; ++g) {
            f32x4 v;
            v[0] = xs[kk * 32 + g * 4 + 0][n];
            v[1] = xs[kk * 32 + g * 4 + 1][n];
            v[2] = xs[kk * 32 + g * 4 + 2][n];
            v[3] = xs[kk * 32 + g * 4 + 3][n];
            *(f32x4*)(fo + g * 4) = v;
        }
    }
}

// ---------------- main MFMA kernel (r11 skeleton, 32 p/wave, 8 n-pieces) ----------------
// grid 2048 = (16 ptile x 16 b x 8 n-pieces) XCD-swizzled; block 256 = 4 waves
// = 4 psg x 32 p each (TWO B-fragment sets). Pieces: 4x25 + 4x24 chunks.
// Counted-vmcnt(2): chunk t staged at body t-3 (clamped); vmcnt then barrier.
// 8 blocks/CU (20KB LDS), launch_bounds (256,8): 64-VGPR budget, demand ~44.
__global__ __launch_bounds__(256, 8)
void proto_mfma(const unsigned short* __restrict__ xt,
                const unsigned short* __restrict__ pt,
                const float* __restrict__ x2,
                unsigned* __restrict__ k1w, unsigned* __restrict__ k2w) {
    // hand-placed LDS: [0,4K) x2s (<=400 used) | [4K,20K) As[4buf][4K]
    __shared__ __align__(16) char LDS[20480];
    float* x2s = (float*)LDS;
    char*  AsB = LDS + 4096;

    int lid = blockIdx.x;                      // 0..2047
    int sid = (lid & 7) * 256 + (lid >> 3);    // bijective XCD chunking (2048%8==0)
    int b = sid >> 7;                          // 16 b
    int rest = sid & 127;
    int pbase = (rest >> 3) * 128;             // 16 ptiles of 128
    int q8 = rest & 7;                         // 8 n-pieces

    int L = (q8 < 4) ? 25 : 24;                // chunks in this piece
    int start = (q8 < 4) ? q8 * 25 : 100 + (q8 - 4) * 24;

    int tid = threadIdx.x;
    int lane = tid & 63, psg = tid >> 6;       // 4 p-groups of 32p, shared n-stream
    int l15 = lane & 15, lg = lane >> 4;

    // B fragments: 2 sets x 4 named bf16x8 (32 VGPR), resident
    const unsigned short* bpa = pt + (size_t)(pbase + psg * 32 + l15) * 128 + lg * 8;
    const unsigned short* bpb = bpa + (size_t)16 * 128;
    bf16x8 Ba0 = *(const bf16x8*)(bpa);
    bf16x8 Ba1 = *(const bf16x8*)(bpa + 32);
    bf16x8 Ba2 = *(const bf16x8*)(bpa + 64);
    bf16x8 Ba3 = *(const bf16x8*)(bpa + 96);
    bf16x8 Bb0 = *(const bf16x8*)(bpb);
    bf16x8 Bb1 = *(const bf16x8*)(bpb + 32);
    bf16x8 Bb2 = *(const bf16x8*)(bpb + 64);
    bf16x8 Bb3 = *(const bf16x8*)(bpb + 96);

    const char* srcBase = (const char*)xt + ((size_t)b * NCHUNK + start) * 4096;
    const char* aread = AsB + lane * 16;       // + buf*4096 + kk*1024
    const int qOfs = start * 16;
    const int nbBase = qOfs + lg * 4;          // + chunk*16 + rr

    unsigned K1a = 0xFFFFFFFFu, K2a = 0xFFFFFFFFu;
    unsigned K1b = 0xFFFFFFFFu, K2b = 0xFFFFFFFFu;

    // ---- prologue: x2 piece slice (2 dword-DMAs, clamped) + chunks 0,1,2 ----
    {
        const float* xsrc = x2 + (size_t)b * NPTS + qOfs;
        #pragma unroll
        for (int r = 0; r < 2; ++r)
            gload_lds4(xsrc + min(r * 256 + psg * 64 + lane, L * 16 - 1),
                       (char*)x2s + (r * 256 + psg * 64) * 4);
    }
    #pragma unroll
    for (int r = 0; r < 3; ++r)
        gload_lds16(srcBase + (size_t)r * 4096 + psg * 1024 + (size_t)lane * 16,
                    AsB + r * 4096 + psg * 1024);

    // Body: 1 chunk-DMA per wave per body; vmcnt(2) retires chunk T's loads
    // (in-order; x2 loads issued first retire first). Barrier AFTER the wait.
#define PMF_TRACK(ACC, XV, NB, K1, K2)                                              \
        _Pragma("unroll")                                                           \
        for (int rr = 0; rr < 4; ++rr) {                                            \
            float f = fmaf((ACC)[rr], -1024.f, (XV)[rr]);                           \
            unsigned k = ((unsigned)f << 12) | (unsigned)((NB) + rr);               \
            K2 = min(K2, max(K1, k));                                               \
            K1 = min(K1, k);                                                        \
        }

#define PMF_BODY(T, U)                                                              \
    {                                                                               \
        asm volatile("s_waitcnt vmcnt(2)" ::: "memory");                            \
        __builtin_amdgcn_s_barrier();                                               \
        int cln = (T) + 3;                                                          \
        cln = cln > L - 1 ? L - 1 : cln;                                            \
        gload_lds16(srcBase + (size_t)cln * 4096 + psg * 1024 + (size_t)lane * 16,  \
                    AsB + (((U) + 3) & 3) * 4096 + psg * 1024);                     \
        f32x4 xv = *(const f32x4*)&x2s[(T) * 16 + lg * 4];                          \
        const char* ar = aread + (U) * 4096;                                        \
        bf16x8 A0 = *(const bf16x8*)(ar);                                           \
        bf16x8 A1 = *(const bf16x8*)(ar + 1024);                                    \
        bf16x8 A2 = *(const bf16x8*)(ar + 2048);                                    \
        bf16x8 A3 = *(const bf16x8*)(ar + 3072);                                    \
        f32x4 accA = {0.f, 0.f, 0.f, 0.f};                                          \
        f32x4 accB = {0.f, 0.f, 0.f, 0.f};                                          \
        __builtin_amdgcn_s_setprio(1);                                              \
        accA = __builtin_amdgcn_mfma_f32_16x16x32_bf16(A0, Ba0, accA, 0, 0, 0);     \
        accB = __builtin_amdgcn_mfma_f32_16x16x32_bf16(A0, Bb0, accB, 0, 0, 0);     \
        accA = __builtin_amdgcn_mfma_f32_16x16x32_bf16(A1, Ba1, accA, 0, 0, 0);     \
        accB = __builtin_amdgcn_mfma_f32_16x16x32_bf16(A1, Bb1, accB, 0, 0, 0);     \
        accA = __builtin_amdgcn_mfma_f32_16x16x32_bf16(A2, Ba2, accA, 0, 0, 0);     \
        accB = __builtin_amdgcn_mfma_f32_16x16x32_bf16(A2, Bb2, accB, 0, 0, 0);     \
        accA = __builtin_amdgcn_mfma_f32_16x16x32_bf16(A3, Ba3, accA, 0, 0, 0);     \
        accB = __builtin_amdgcn_mfma_f32_16x16x32_bf16(A3, Bb3, accB, 0, 0, 0);     \
        __builtin_amdgcn_s_setprio(0);                                              \
        int nb = nbBase + (T) * 16;                                                 \
        PMF_TRACK(accA, xv, nb, K1a, K2a)                                           \
        PMF_TRACK(accB, xv, nb, K1b, K2b)                                           \
    }

    // 24 bodies in 6 unrolled groups; L==25 pieces run one extra body (buf 0).
    #pragma unroll 1
    for (int t0 = 0; t0 < 24; t0 += 4) {
        PMF_BODY(t0 + 0, 0)
        PMF_BODY(t0 + 1, 1)
        PMF_BODY(t0 + 2, 2)
        PMF_BODY(t0 + 3, 3)
    }
    if (L == 25) {
        PMF_BODY(24, 0)
    }
#undef PMF_BODY
#undef PMF_TRACK

    // ---- reduce across the 4 row-groups (lanes l, l+16, l+32, l+48) ----
    #pragma unroll
    for (int m = 16; m <= 32; m <<= 1) {
        unsigned c1a = (unsigned)__shfl_xor((int)K1a, m, 64);
        unsigned c2a = (unsigned)__shfl_xor((int)K2a, m, 64);
        unsigned wa  = max(K1a, c1a);
        K1a = min(K1a, c1a);
        K2a = min(wa, min(K2a, c2a));
        unsigned c1b = (unsigned)__shfl_xor((int)K1b, m, 64);
        unsigned c2b = (unsigned)__shfl_xor((int)K2b, m, 64);
        unsigned wb  = max(K1b, c1b);
        K1b = min(K1b, c1b);
        K2b = min(wb, min(K2b, c2b));
    }
    // each wave owns 32 distinct p -> direct global writes, no cross-wave reduce
    if (lg == 0) {
        size_t o = ((size_t)b * 8 + q8) * PPAD + pbase + psg * 32 + l15;
        k1w[o] = K1a;
        k2w[o] = K2a;
        k1w[o + 16] = K1b;
        k2w[o + 16] = K2b;
    }
}

// ---------------- exact fp32 fixup: merge 8 piece-top-2s -> half-top-2 (4 cand) ----------------
// Pieces are disjoint in n, so key-merges are EXACT: top2(half) from 4 pieces'
// (top1,top2). Coverage identical to the proven r11/r14/r15 scheme.
template<int MODE>
__global__ __launch_bounds__(256)
void fixup(const float* __restrict__ x, const float* __restrict__ xfT,
           const float* __restrict__ proto,
           const unsigned* __restrict__ k1w, const unsigned* __restrict__ k2w,
           float* __restrict__ out) {
    int tid = threadIdx.x;
    int lane = tid & 63, wv = tid >> 6;
    long long pair = (long long)blockIdx.x * 4 + wv;
    if (pair >= (long long)BATCH * PROT) return;
    int b = (int)(pair / PROT), p = (int)(pair % PROT);
    unsigned a[8], c[8];
    #pragma unroll
    for (int qq = 0; qq < 8; ++qq) {
        a[qq] = k1w[((size_t)b * 8 + qq) * PPAD + p];
        c[qq] = k2w[((size_t)b * 8 + qq) * PPAD + p];
    }
    int cand[4];
    #pragma unroll
    for (int h = 0; h < 2; ++h) {
        int o = h * 4;
        unsigned p1a = min(a[o], a[o + 1]);
        unsigned p2a = min(max(a[o], a[o + 1]), min(c[o], c[o + 1]));
        unsigned p1b = min(a[o + 2], a[o + 3]);
        unsigned p2b = min(max(a[o + 2], a[o + 3]), min(c[o + 2], c[o + 3]));
        unsigned h1 = min(p1a, p1b);
        unsigned h2 = min(max(p1a, p1b), min(p2a, p2b));
        cand[h * 2]     = (int)(h1 & 0xFFFu);
        cand[h * 2 + 1] = (int)(h2 & 0xFFFu);
    }

    int d0 = lane, d1 = lane + 64;
    float pa0 = proto[(size_t)p * DDIM + d0], pa1 = proto[(size_t)p * DDIM + d1];
    float sp2 = pa0 * pa0 + pa1 * pa1;
    float f0[4], f1[4], sxp[4], sx2[4];
    #pragma unroll
    for (int cc = 0; cc < 4; ++cc) {
        int n = cand[cc];
        float v0, v1;
        if (MODE == 0) {
            const float* f = xfT + ((size_t)b * NPTS + n) * DDIM;
            v0 = f[d0]; v1 = f[d1];
        } else {
            const float* xb = x + (size_t)b * DDIM * NPTS;
            v0 = xb[(size_t)d0 * NPTS + n]; v1 = xb[(size_t)d1 * NPTS + n];
        }
        f0[cc] = v0; f1[cc] = v1;
        sxp[cc] = v0 * pa0 + v1 * pa1;
        sx2[cc] = v0 * v0 + v1 * v1;
    }
    #pragma unroll
    for (int m = 1; m < 64; m <<= 1) {
        sp2 += __shfl_xor(sp2, m, 64);
        #pragma unroll
        for (int cc = 0; cc < 4; ++cc) {
            sxp[cc] += __shfl_xor(sxp[cc], m, 64);
            sx2[cc] += __shfl_xor(sx2[cc], m, 64);
        }
    }
    float bd = 3e38f; int bn = 0x7FFFFFFF; int bc = 0;
    #pragma unroll
    for (int cc = 0; cc < 4; ++cc) {
        float d2 = fmaxf(sx2[cc] + sp2 - 2.f * sxp[cc], 0.f);
        bool w = (d2 < bd) || (d2 == bd && cand[cc] < bn);
        bd = w ? d2 : bd;
        bn = w ? cand[cc] : bn;
        bc = w ? cc : bc;
    }
    float dm = sqrtf(bd);
    float sim = logf((dm + 1.0f) / (dm + 1e-7f));
    if (lane == 0) {
        out[(size_t)b * PROT + p] = sim;
        out[(size_t)BATCH * PROT + (size_t)b * PROT + p] = dm;
    }
    float o0 = f0[0], o1 = f1[0];
    #pragma unroll
    for (int cc = 1; cc < 4; ++cc) {
        o0 = (bc == cc) ? f0[cc] : o0;
        o1 = (bc == cc) ? f1[cc] : o1;
    }
    float* fo = out + (size_t)2 * BATCH * PROT + ((size_t)b * PROT + p) * DDIM;
    fo[d0] = o0;
    fo[d1] = o1;
}

// ================= fallback fp32 path (round-1, known-good) =================
#define TP 64
#define TN 64
__global__ void p2_kernel(const float* __restrict__ proto, float* __restrict__ p2) {
    int p = blockIdx.x * blockDim.x + threadIdx.x;
    if (p >= PROT) return;
    const float4* pr = reinterpret_cast<const float4*>(proto + (size_t)p * DDIM);
    float s = 0.f;
    #pragma unroll
    for (int i = 0; i < DDIM / 4; ++i) {
        float4 v = pr[i];
        s += v.x * v.x + v.y * v.y + v.z * v.z + v.w * v.w;
    }
    p2[p] = s;
}
__global__ void x2_kernel(const float* __restrict__ x, float* __restrict__ x2) {
    int idx = blockIdx.x * blockDim.x + threadIdx.x;
    if (idx >= BATCH * NPTS) return;
    int b = idx / NPTS, n = idx - b * NPTS;
    const float* xp = x + (size_t)b * DDIM * NPTS + n;
    float s = 0.f;
    #pragma unroll 8
    for (int d = 0; d < DDIM; ++d) { float v = xp[(size_t)d * NPTS]; s += v * v; }
    x2[idx] = s;
}
__global__ __launch_bounds__(256, 2)
void proto_main(const float* __restrict__ x, const float* __restrict__ proto,
                const float* __restrict__ p2, const float* __restrict__ x2,
                float* __restrict__ out) {
    __shared__ __align__(16) float xs[DDIM][TN];
    __shared__ __align__(16) float pst[DDIM][TP];
    __shared__ float p2s[TP];
    __shared__ float x2s[TN];
    __shared__ float red_d2[16][TP];
    __shared__ int   red_n[16][TP];
    __shared__ int   bestn_s[TP];
    const int b = blockIdx.y;
    const int pbase = blockIdx.x * TP;
    const int tid = threadIdx.x;
    {
        #pragma unroll
        for (int it = 0; it < (TP * DDIM / 4) / 256; ++it) {
            int idx = it * 256 + tid;
            int p = idx / (DDIM / 4);
            int dq = idx - p * (DDIM / 4);
            int gp = min(pbase + p, PROT - 1);
            float4 v = reinterpret_cast<const float4*>(proto)[(size_t)gp * (DDIM / 4) + dq];
            pst[dq * 4 + 0][p] = v.x; pst[dq * 4 + 1][p] = v.y;
            pst[dq * 4 + 2][p] = v.z; pst[dq * 4 + 3][p] = v.w;
        }
        if (tid < TP) p2s[tid] = p2[min(pbase + tid, PROT - 1)];
    }
    const int tn = tid >> 4;
    const int tp = tid & 15;
    float best[4]; int bestn[4];
    #pragma unroll
    for (int j = 0; j < 4; ++j) { best[j] = 1e30f; bestn[j] = 0; }
    for (int n0 = 0; n0 < NPTS; n0 += TN) {
        __syncthreads();
        {
            int r = tid >> 4, c = tid & 15;
            #pragma unroll
            for (int it = 0; it < 8; ++it) {
                int row = it * 16 + r;
                float4 v = *reinterpret_cast<const float4*>(
                    x + ((size_t)(b * DDIM + row)) * NPTS + n0 + c * 4);
                *reinterpret_cast<float4*>(&xs[row][c * 4]) = v;
            }
        }
        if (tid < TN) x2s[tid] = x2[b * NPTS + n0 + tid];
        __syncthreads();
        float acc[4][4];
        #pragma unroll
        for (int i = 0; i < 4; ++i)
            #pragma unroll
            for (int j = 0; j < 4; ++j) acc[i][j] = 0.f;
        #pragma unroll 16
        for (int d = 0; d < DDIM; ++d) {
            const float4 a = *reinterpret_cast<const float4*>(&xs[d][tn * 4]);
            const float4 bv = *reinterpret_cast<const float4*>(&pst[d][tp * 4]);
            const float av[4] = {a.x, a.y, a.z, a.w};
            const float bw[4] = {bv.x, bv.y, bv.z, bv.w};
            #pragma unroll
            for (int i = 0; i < 4; ++i)
                #pragma unroll
                for (int j = 0; j < 4; ++j) acc[i][j] = fmaf(av[i], bw[j], acc[i][j]);
        }
        #pragma unroll
        for (int i = 0; i < 4; ++i) {
            float xv = x2s[tn * 4 + i];
            int n = n0 + tn * 4 + i;
            #pragma unroll
            for (int j = 0; j < 4; ++j) {
                float d2 = xv + p2s[tp * 4 + j] - 2.0f * acc[i][j];
                if (d2 < best[j]) { best[j] = d2; bestn[j] = n; }
            }
        }
    }
    #pragma unroll
    for (int j = 0; j < 4; ++j) {
        red_d2[tn][tp * 4 + j] = best[j];
        red_n[tn][tp * 4 + j] = bestn[j];
    }
    __syncthreads();
    if (tid < TP) {
        float bd = red_d2[0][tid]; int bn = red_n[0][tid];
        #pragma unroll
        for (int t = 1; t < 16; ++t) {
            float dv = red_d2[t][tid]; int nv = red_n[t][tid];
            if (dv < bd || (dv == bd && nv < bn)) { bd = dv; bn = nv; }
        }
        int gp = pbase + tid;
        if (gp < PROT) {
            float d2c = fmaxf(bd, 0.f);
            float dmin = sqrtf(d2c);
            float sim = logf((dmin + 1.0f) / (dmin + 1e-7f));
            out[(size_t)b * PROT + gp] = sim;
            out[(size_t)BATCH * PROT + (size_t)b * PROT + gp] = dmin;
        }
        bestn_s[tid] = bn;
    }
    __syncthreads();
    {
        int pl = tid >> 2, dbase = (tid & 3) * 32;
        int gp = pbase + pl;
        if (gp < PROT) {
            int n = bestn_s[pl];
            float* dst = out + (size_t)2 * BATCH * PROT + ((size_t)(b * PROT + gp)) * DDIM + dbase;
            const float* src = x + ((size_t)(b * DDIM + dbase)) * NPTS + n;
            #pragma unroll 8
            for (int d = 0; d < 32; ++d) dst[d] = src[(size_t)d * NPTS];
        }
    }
}

extern "C" void kernel_launch(void* const* d_in, const int* in_sizes, int n_in,
                              void* d_out, int out_size, void* d_ws, size_t ws_size,
                              hipStream_t stream) {
    const float* x = (const float*)d_in[0];       // [16,128,56,56]
    const float* proto = (const float*)d_in[1];   // [1,2000,128]
    float* out = (float*)d_out;
    float* ws = (float*)d_ws;

    if (ws_size >= WS_MID) {
        bool big = (ws_size >= WS_BIG);
        float* x2 = ws + WS_X2;
        unsigned* k1w = (unsigned*)(ws + WS_K1);
        unsigned* k2w = (unsigned*)(ws + WS_K2);
        unsigned short* pt = (unsigned short*)(ws + WS_PT);
        unsigned short* xt = (unsigned short*)(ws + WS_XT);
        float* xfT = big ? (ws + WS_XFT) : nullptr;

        pp_fused<<<dim3(50, BATCH), 256, 0, stream>>>(x, proto, xt, pt, x2, xfT);
        proto_mfma<<<2048, 256, 0, stream>>>(xt, pt, x2, k1w, k2w);
        if (big)
            fixup<0><<<(BATCH * PROT) / 4, 256, 0, stream>>>(x, xfT, proto, k1w, k2w, out);
        else
            fixup<1><<<(BATCH * PROT) / 4, 256, 0, stream>>>(x, nullptr, proto, k1w, k2w, out);
    } else {
        float* p2 = ws;
        float* x2 = ws + 2048;
        p2_kernel<<<(PROT + 255) / 256, 256, 0, stream>>>(proto, p2);
        x2_kernel<<<(BATCH * NPTS + 255) / 256, 256, 0, stream>>>(x, x2);
        dim3 grid((PROT + TP - 1) / TP, BATCH);
        proto_main<<<grid, 256, 0, stream>>>(x, proto, p2, x2, out);
    }
}

// Round 17
// 77.237 us; speedup vs baseline: 1.8329x; 1.8329x over previous
//
#include <hip/hip_runtime.h>
#include <hip/hip_bf16.h>
#include <cmath>

#define DDIM 128
#define NPTS 3136   // 56*56
#define NCHUNK 196  // NPTS/16
#define BATCH 16
#define PROT 2000
#define PPAD 2048   // 16 tiles * 128

typedef __attribute__((ext_vector_type(8))) short bf16x8;
typedef __attribute__((ext_vector_type(4))) float f32x4;
typedef __attribute__((ext_vector_type(4))) unsigned int u32x4;

// ---- workspace layout (float/u32 slot indices) ----
#define WS_X2   0                      // 50176
#define WS_K1   50176                  // 262144 (16 b x 8 piece slots x 2048; 6 used)
#define WS_K2   312320                 // 262144
#define WS_PT   574464                 // 131072 slots (= 262144 shorts, 2048x128)
#define WS_XT   705536                 // 3211264 slots (= 16*196*4096 bytes)
#define WS_XFT  3916800                // 6422528 (16*3136*128 f32)
#define WS_MID  ((size_t)3916800 * 4)
#define WS_BIG  ((size_t)10339328 * 4)

// ---------------- bf16 helpers ----------------
__device__ inline unsigned short bf16rn(float a) {
    unsigned u = __float_as_uint(a);
    unsigned r = u + 0x7FFFu + ((u >> 16) & 1u);
    return (unsigned short)(r >> 16);
}

__device__ __forceinline__ void gload_lds16(const void* g, void* l) {
    __builtin_amdgcn_global_load_lds(
        (const __attribute__((address_space(1))) void*)g,
        (__attribute__((address_space(3))) void*)l, 16, 0, 0);
}
__device__ __forceinline__ void gload_lds4(const void* g, void* l) {
    __builtin_amdgcn_global_load_lds(
        (const __attribute__((address_space(1))) void*)g,
        (__attribute__((address_space(3))) void*)l, 4, 0, 0);
}

// ---------------- fused pre-pass (unchanged, proven) ----------------
__global__ __launch_bounds__(256)
void pp_fused(const float* __restrict__ x, const float* __restrict__ proto,
              unsigned short* __restrict__ xt, unsigned short* __restrict__ pt,
              float* __restrict__ x2, float* __restrict__ xfT) {
    int tid = threadIdx.x;
    if (blockIdx.x == 49) {               // prototype part: 8 blocks x 256 = 2048
        int by = blockIdx.y;
        if (by >= 8) return;
        int p = by * 256 + tid;           // 0..2047
        int ps = min(p, PROT - 1);
        const float* src = proto + (size_t)ps * DDIM;
        unsigned short* dst = pt + (size_t)p * 128;
        for (int j = 0; j < DDIM; ++j) dst[j] = bf16rn(src[j]);
        return;
    }
    __shared__ float xs[DDIM][64];
    int b = blockIdx.y;
    int n0 = blockIdx.x * 64;
    {
        int r = tid >> 4, c = tid & 15;
        #pragma unroll
        for (int it = 0; it < 8; ++it) {
            int row = it * 16 + r;
            f32x4 v = *(const f32x4*)(x + ((size_t)(b * DDIM + row)) * NPTS + n0 + c * 4);
            *(f32x4*)(&xs[row][c * 4]) = v;
        }
    }
    __syncthreads();
    if (tid < 64) {
        float s = 0.f;
        #pragma unroll 8
        for (int d = 0; d < DDIM; ++d) { float v = xs[d][tid]; s = fmaf(v, v, s); }
        x2[b * NPTS + n0 + tid] = (s + 512.0f) * 512.0f;
    }
    int n = tid & 63, kk = tid >> 6;
    int nl = n & 15, ci = (n0 + n) >> 4;
    unsigned int hw[16];
    #pragma unroll
    for (int j = 0; j < 16; ++j) {
        unsigned short h0 = bf16rn(xs[kk * 32 + 2 * j][n]);
        unsigned short h1 = bf16rn(xs[kk * 32 + 2 * j + 1][n]);
        hw[j] = (unsigned)h0 | ((unsigned)h1 << 16);
    }
    char* cb = (char*)xt + ((size_t)b * NCHUNK + ci) * 4096;
    #pragma unroll
    for (int g = 0; g < 4; ++g)
        *(u32x4*)(cb + kk * 1024 + g * 256 + nl * 16) = *(u32x4*)(&hw[g * 4]);
    if (xfT) {
        float* fo = xfT + ((size_t)b * NPTS + n0 + n) * DDIM + kk * 32;
        #pragma unroll
        for (int g = 0; g < 8; ++g) {
            f32x4 v;
            v[0] = xs[kk * 32 + g * 4 + 0][n];
            v[1] = xs[kk * 32 + g * 4 + 1][n];
            v[2] = xs[kk * 32 + g * 4 + 2][n];
            v[3] = xs[kk * 32 + g * 4 + 3][n];
            *(f32x4*)(fo + g * 4) = v;
        }
    }
}

// ---------------- main MFMA kernel (r15 body, 6 n-pieces, 6 blocks/CU) ----------------
// grid 1536 = (16 ptile x 16 b x 6 n-pieces) XCD-swizzled; block 256 = 4 waves
// = 4 psg x 32 p each (TWO B-fragment sets). Pieces: 4x33 + 2x32 chunks.
// Counted-vmcnt(2): chunk t staged at body t-3 (clamped); vmcnt then barrier.
// launch_bounds (256,6): ~84-VGPR budget >= ~80 demand -> no spill (watch WRITE_SIZE).
__global__ __launch_bounds__(256, 6)
void proto_mfma(const unsigned short* __restrict__ xt,
                const unsigned short* __restrict__ pt,
                const float* __restrict__ x2,
                unsigned* __restrict__ k1w, unsigned* __restrict__ k2w) {
    // hand-placed LDS: [0,4K) x2s (<=528 used) | [4K,20K) As[4buf][4K]
    __shared__ __align__(16) char LDS[20480];
    float* x2s = (float*)LDS;
    char*  AsB = LDS + 4096;

    int lid = blockIdx.x;                      // 0..1535
    int sid = (lid & 7) * 192 + (lid >> 3);    // bijective XCD chunking (1536%8==0)
    int b = sid / 96;                          // 16 b
    int rest = sid - b * 96;
    int pbase = (rest / 6) * 128;              // 16 ptiles of 128
    int q6 = rest % 6;                         // 6 n-pieces

    int L = (q6 < 4) ? 33 : 32;                // chunks in this piece
    int start = (q6 < 4) ? q6 * 33 : 132 + (q6 - 4) * 32;

    int tid = threadIdx.x;
    int lane = tid & 63, psg = tid >> 6;       // 4 p-groups of 32p, shared n-stream
    int l15 = lane & 15, lg = lane >> 4;

    // B fragments: 2 sets x 4 named bf16x8 (32 VGPR), resident
    const unsigned short* bpa = pt + (size_t)(pbase + psg * 32 + l15) * 128 + lg * 8;
    const unsigned short* bpb = bpa + (size_t)16 * 128;
    bf16x8 Ba0 = *(const bf16x8*)(bpa);
    bf16x8 Ba1 = *(const bf16x8*)(bpa + 32);
    bf16x8 Ba2 = *(const bf16x8*)(bpa + 64);
    bf16x8 Ba3 = *(const bf16x8*)(bpa + 96);
    bf16x8 Bb0 = *(const bf16x8*)(bpb);
    bf16x8 Bb1 = *(const bf16x8*)(bpb + 32);
    bf16x8 Bb2 = *(const bf16x8*)(bpb + 64);
    bf16x8 Bb3 = *(const bf16x8*)(bpb + 96);

    const char* srcBase = (const char*)xt + ((size_t)b * NCHUNK + start) * 4096;
    const char* aread = AsB + lane * 16;       // + buf*4096 + kk*1024
    const int qOfs = start * 16;
    const int nbBase = qOfs + lg * 4;          // + chunk*16 + rr

    unsigned K1a = 0xFFFFFFFFu, K2a = 0xFFFFFFFFu;
    unsigned K1b = 0xFFFFFFFFu, K2b = 0xFFFFFFFFu;

    // ---- prologue: x2 piece slice (3 dword-DMAs, clamped; 768>=528) + chunks 0,1,2 ----
    {
        const float* xsrc = x2 + (size_t)b * NPTS + qOfs;
        #pragma unroll
        for (int r = 0; r < 3; ++r)
            gload_lds4(xsrc + min(r * 256 + psg * 64 + lane, L * 16 - 1),
                       (char*)x2s + (r * 256 + psg * 64) * 4);
    }
    #pragma unroll
    for (int r = 0; r < 3; ++r)
        gload_lds16(srcBase + (size_t)r * 4096 + psg * 1024 + (size_t)lane * 16,
                    AsB + r * 4096 + psg * 1024);

    // Body: 1 chunk-DMA per wave per body; vmcnt(2) retires chunk T's loads
    // (in-order: 3 x2 DMAs + chunks 0..T retired when <=2 remain). Barrier after.
#define PMF_TRACK(ACC, XV, NB, K1, K2)                                              \
        _Pragma("unroll")                                                           \
        for (int rr = 0; rr < 4; ++rr) {                                            \
            float f = fmaf((ACC)[rr], -1024.f, (XV)[rr]);                           \
            unsigned k = ((unsigned)f << 12) | (unsigned)((NB) + rr);               \
            K2 = min(K2, max(K1, k));                                               \
            K1 = min(K1, k);                                                        \
        }

#define PMF_BODY(T, U)                                                              \
    {                                                                               \
        asm volatile("s_waitcnt vmcnt(2)" ::: "memory");                            \
        __builtin_amdgcn_s_barrier();                                               \
        int cln = (T) + 3;                                                          \
        cln = cln > L - 1 ? L - 1 : cln;                                            \
        gload_lds16(srcBase + (size_t)cln * 4096 + psg * 1024 + (size_t)lane * 16,  \
                    AsB + (((U) + 3) & 3) * 4096 + psg * 1024);                     \
        f32x4 xv = *(const f32x4*)&x2s[(T) * 16 + lg * 4];                          \
        const char* ar = aread + (U) * 4096;                                        \
        bf16x8 A0 = *(const bf16x8*)(ar);                                           \
        bf16x8 A1 = *(const bf16x8*)(ar + 1024);                                    \
        bf16x8 A2 = *(const bf16x8*)(ar + 2048);                                    \
        bf16x8 A3 = *(const bf16x8*)(ar + 3072);                                    \
        f32x4 accA = {0.f, 0.f, 0.f, 0.f};                                          \
        f32x4 accB = {0.f, 0.f, 0.f, 0.f};                                          \
        __builtin_amdgcn_s_setprio(1);                                              \
        accA = __builtin_amdgcn_mfma_f32_16x16x32_bf16(A0, Ba0, accA, 0, 0, 0);     \
        accB = __builtin_amdgcn_mfma_f32_16x16x32_bf16(A0, Bb0, accB, 0, 0, 0);     \
        accA = __builtin_amdgcn_mfma_f32_16x16x32_bf16(A1, Ba1, accA, 0, 0, 0);     \
        accB = __builtin_amdgcn_mfma_f32_16x16x32_bf16(A1, Bb1, accB, 0, 0, 0);     \
        accA = __builtin_amdgcn_mfma_f32_16x16x32_bf16(A2, Ba2, accA, 0, 0, 0);     \
        accB = __builtin_amdgcn_mfma_f32_16x16x32_bf16(A2, Bb2, accB, 0, 0, 0);     \
        accA = __builtin_amdgcn_mfma_f32_16x16x32_bf16(A3, Ba3, accA, 0, 0, 0);     \
        accB = __builtin_amdgcn_mfma_f32_16x16x32_bf16(A3, Bb3, accB, 0, 0, 0);     \
        __builtin_amdgcn_s_setprio(0);                                              \
        int nb = nbBase + (T) * 16;                                                 \
        PMF_TRACK(accA, xv, nb, K1a, K2a)                                           \
        PMF_TRACK(accB, xv, nb, K1b, K2b)                                           \
    }

    // 32 bodies in 8 unrolled groups; L==33 pieces run one extra body (32&3==0 -> buf 0).
    #pragma unroll 1
    for (int t0 = 0; t0 < 32; t0 += 4) {
        PMF_BODY(t0 + 0, 0)
        PMF_BODY(t0 + 1, 1)
        PMF_BODY(t0 + 2, 2)
        PMF_BODY(t0 + 3, 3)
    }
    if (L == 33) {
        PMF_BODY(32, 0)
    }
#undef PMF_BODY
#undef PMF_TRACK

    // ---- reduce across the 4 row-groups (lanes l, l+16, l+32, l+48) ----
    #pragma unroll
    for (int m = 16; m <= 32; m <<= 1) {
        unsigned c1a = (unsigned)__shfl_xor((int)K1a, m, 64);
        unsigned c2a = (unsigned)__shfl_xor((int)K2a, m, 64);
        unsigned wa  = max(K1a, c1a);
        K1a = min(K1a, c1a);
        K2a = min(wa, min(K2a, c2a));
        unsigned c1b = (unsigned)__shfl_xor((int)K1b, m, 64);
        unsigned c2b = (unsigned)__shfl_xor((int)K2b, m, 64);
        unsigned wb  = max(K1b, c1b);
        K1b = min(K1b, c1b);
        K2b = min(wb, min(K2b, c2b));
    }
    // each wave owns 32 distinct p -> direct global writes, no cross-wave reduce
    if (lg == 0) {
        size_t o = ((size_t)b * 8 + q6) * PPAD + pbase + psg * 32 + l15;
        k1w[o] = K1a;
        k2w[o] = K2a;
        k1w[o + 16] = K1b;
        k2w[o + 16] = K2b;
    }
}

// ---------------- exact fp32 fixup: merge 6 piece-top-2s -> 2 triplet-top-2s ----------------
// Pieces disjoint in n; within a piece a<=c. For a triplet, top1=min(a); top2 =
// min(second_min(a), min(c)) is EXACT (non-best pieces' c >= their a >= second_min(a)).
// 4 candidates = top-2 over each ~half of n. Same coverage class as the proven scheme.
template<int MODE>
__global__ __launch_bounds__(256)
void fixup(const float* __restrict__ x, const float* __restrict__ xfT,
           const float* __restrict__ proto,
           const unsigned* __restrict__ k1w, const unsigned* __restrict__ k2w,
           float* __restrict__ out) {
    int tid = threadIdx.x;
    int lane = tid & 63, wv = tid >> 6;
    long long pair = (long long)blockIdx.x * 4 + wv;
    if (pair >= (long long)BATCH * PROT) return;
    int b = (int)(pair / PROT), p = (int)(pair % PROT);
    unsigned a[6], c[6];
    #pragma unroll
    for (int qq = 0; qq < 6; ++qq) {
        a[qq] = k1w[((size_t)b * 8 + qq) * PPAD + p];
        c[qq] = k2w[((size_t)b * 8 + qq) * PPAD + p];
    }
    int cand[4];
    #pragma unroll
    for (int h = 0; h < 2; ++h) {
        int o = h * 3;
        unsigned lo = min(a[o], a[o + 1]);
        unsigned hi = max(a[o], a[o + 1]);
        unsigned t1 = min(lo, a[o + 2]);
        unsigned sec = min(hi, max(lo, a[o + 2]));           // second smallest of firsts
        unsigned t2 = min(sec, min(c[o], min(c[o + 1], c[o + 2])));
        cand[h * 2]     = (int)(t1 & 0xFFFu);
        cand[h * 2 + 1] = (int)(t2 & 0xFFFu);
    }

    int d0 = lane, d1 = lane + 64;
    float pa0 = proto[(size_t)p * DDIM + d0], pa1 = proto[(size_t)p * DDIM + d1];
    float sp2 = pa0 * pa0 + pa1 * pa1;
    float f0[4], f1[4], sxp[4], sx2[4];
    #pragma unroll
    for (int cc = 0; cc < 4; ++cc) {
        int n = cand[cc];
        float v0, v1;
        if (MODE == 0) {
            const float* f = xfT + ((size_t)b * NPTS + n) * DDIM;
            v0 = f[d0]; v1 = f[d1];
        } else {
            const float* xb = x + (size_t)b * DDIM * NPTS;
            v0 = xb[(size_t)d0 * NPTS + n]; v1 = xb[(size_t)d1 * NPTS + n];
        }
        f0[cc] = v0; f1[cc] = v1;
        sxp[cc] = v0 * pa0 + v1 * pa1;
        sx2[cc] = v0 * v0 + v1 * v1;
    }
    #pragma unroll
    for (int m = 1; m < 64; m <<= 1) {
        sp2 += __shfl_xor(sp2, m, 64);
        #pragma unroll
        for (int cc = 0; cc < 4; ++cc) {
            sxp[cc] += __shfl_xor(sxp[cc], m, 64);
            sx2[cc] += __shfl_xor(sx2[cc], m, 64);
        }
    }
    float bd = 3e38f; int bn = 0x7FFFFFFF; int bc = 0;
    #pragma unroll
    for (int cc = 0; cc < 4; ++cc) {
        float d2 = fmaxf(sx2[cc] + sp2 - 2.f * sxp[cc], 0.f);
        bool w = (d2 < bd) || (d2 == bd && cand[cc] < bn);
        bd = w ? d2 : bd;
        bn = w ? cand[cc] : bn;
        bc = w ? cc : bc;
    }
    float dm = sqrtf(bd);
    float sim = logf((dm + 1.0f) / (dm + 1e-7f));
    if (lane == 0) {
        out[(size_t)b * PROT + p] = sim;
        out[(size_t)BATCH * PROT + (size_t)b * PROT + p] = dm;
    }
    float o0 = f0[0], o1 = f1[0];
    #pragma unroll
    for (int cc = 1; cc < 4; ++cc) {
        o0 = (bc == cc) ? f0[cc] : o0;
        o1 = (bc == cc) ? f1[cc] : o1;
    }
    float* fo = out + (size_t)2 * BATCH * PROT + ((size_t)b * PROT + p) * DDIM;
    fo[d0] = o0;
    fo[d1] = o1;
}

// ================= fallback fp32 path (round-1, known-good) =================
#define TP 64
#define TN 64
__global__ void p2_kernel(const float* __restrict__ proto, float* __restrict__ p2) {
    int p = blockIdx.x * blockDim.x + threadIdx.x;
    if (p >= PROT) return;
    const float4* pr = reinterpret_cast<const float4*>(proto + (size_t)p * DDIM);
    float s = 0.f;
    #pragma unroll
    for (int i = 0; i < DDIM / 4; ++i) {
        float4 v = pr[i];
        s += v.x * v.x + v.y * v.y + v.z * v.z + v.w * v.w;
    }
    p2[p] = s;
}
__global__ void x2_kernel(const float* __restrict__ x, float* __restrict__ x2) {
    int idx = blockIdx.x * blockDim.x + threadIdx.x;
    if (idx >= BATCH * NPTS) return;
    int b = idx / NPTS, n = idx - b * NPTS;
    const float* xp = x + (size_t)b * DDIM * NPTS + n;
    float s = 0.f;
    #pragma unroll 8
    for (int d = 0; d < DDIM; ++d) { float v = xp[(size_t)d * NPTS]; s += v * v; }
    x2[idx] = s;
}
__global__ __launch_bounds__(256, 2)
void proto_main(const float* __restrict__ x, const float* __restrict__ proto,
                const float* __restrict__ p2, const float* __restrict__ x2,
                float* __restrict__ out) {
    __shared__ __align__(16) float xs[DDIM][TN];
    __shared__ __align__(16) float pst[DDIM][TP];
    __shared__ float p2s[TP];
    __shared__ float x2s[TN];
    __shared__ float red_d2[16][TP];
    __shared__ int   red_n[16][TP];
    __shared__ int   bestn_s[TP];
    const int b = blockIdx.y;
    const int pbase = blockIdx.x * TP;
    const int tid = threadIdx.x;
    {
        #pragma unroll
        for (int it = 0; it < (TP * DDIM / 4) / 256; ++it) {
            int idx = it * 256 + tid;
            int p = idx / (DDIM / 4);
            int dq = idx - p * (DDIM / 4);
            int gp = min(pbase + p, PROT - 1);
            float4 v = reinterpret_cast<const float4*>(proto)[(size_t)gp * (DDIM / 4) + dq];
            pst[dq * 4 + 0][p] = v.x; pst[dq * 4 + 1][p] = v.y;
            pst[dq * 4 + 2][p] = v.z; pst[dq * 4 + 3][p] = v.w;
        }
        if (tid < TP) p2s[tid] = p2[min(pbase + tid, PROT - 1)];
    }
    const int tn = tid >> 4;
    const int tp = tid & 15;
    float best[4]; int bestn[4];
    #pragma unroll
    for (int j = 0; j < 4; ++j) { best[j] = 1e30f; bestn[j] = 0; }
    for (int n0 = 0; n0 < NPTS; n0 += TN) {
        __syncthreads();
        {
            int r = tid >> 4, c = tid & 15;
            #pragma unroll
            for (int it = 0; it < 8; ++it) {
                int row = it * 16 + r;
                float4 v = *reinterpret_cast<const float4*>(
                    x + ((size_t)(b * DDIM + row)) * NPTS + n0 + c * 4);
                *reinterpret_cast<float4*>(&xs[row][c * 4]) = v;
            }
        }
        if (tid < TN) x2s[tid] = x2[b * NPTS + n0 + tid];
        __syncthreads();
        float acc[4][4];
        #pragma unroll
        for (int i = 0; i < 4; ++i)
            #pragma unroll
            for (int j = 0; j < 4; ++j) acc[i][j] = 0.f;
        #pragma unroll 16
        for (int d = 0; d < DDIM; ++d) {
            const float4 a = *reinterpret_cast<const float4*>(&xs[d][tn * 4]);
            const float4 bv = *reinterpret_cast<const float4*>(&pst[d][tp * 4]);
            const float av[4] = {a.x, a.y, a.z, a.w};
            const float bw[4] = {bv.x, bv.y, bv.z, bv.w};
            #pragma unroll
            for (int i = 0; i < 4; ++i)
                #pragma unroll
                for (int j = 0; j < 4; ++j) acc[i][j] = fmaf(av[i], bw[j], acc[i][j]);
        }
        #pragma unroll
        for (int i = 0; i < 4; ++i) {
            float xv = x2s[tn * 4 + i];
            int n = n0 + tn * 4 + i;
            #pragma unroll
            for (int j = 0; j < 4; ++j) {
                float d2 = xv + p2s[tp * 4 + j] - 2.0f * acc[i][j];
                if (d2 < best[j]) { best[j] = d2; bestn[j] = n; }
            }
        }
    }
    #pragma unroll
    for (int j = 0; j < 4; ++j) {
        red_d2[tn][tp * 4 + j] = best[j];
        red_n[tn][tp * 4 + j] = bestn[j];
    }
    __syncthreads();
    if (tid < TP) {
        float bd = red_d2[0][tid]; int bn = red_n[0][tid];
        #pragma unroll
        for (int t = 1; t < 16; ++t) {
            float dv = red_d2[t][tid]; int nv = red_n[t][tid];
            if (dv < bd || (dv == bd && nv < bn)) { bd = dv; bn = nv; }
        }
        int gp = pbase + tid;
        if (gp < PROT) {
            float d2c = fmaxf(bd, 0.f);
            float dmin = sqrtf(d2c);
            float sim = logf((dmin + 1.0f) / (dmin + 1e-7f));
            out[(size_t)b * PROT + gp] = sim;
            out[(size_t)BATCH * PROT + (size_t)b * PROT + gp] = dmin;
        }
        bestn_s[tid] = bn;
    }
    __syncthreads();
    {
        int pl = tid >> 2, dbase = (tid & 3) * 32;
        int gp = pbase + pl;
        if (gp < PROT) {
            int n = bestn_s[pl];
            float* dst = out + (size_t)2 * BATCH * PROT + ((size_t)(b * PROT + gp)) * DDIM + dbase;
            const float* src = x + ((size_t)(b * DDIM + dbase)) * NPTS + n;
            #pragma unroll 8
            for (int d = 0; d < 32; ++d) dst[d] = src[(size_t)d * NPTS];
        }
    }
}

extern "C" void kernel_launch(void* const* d_in, const int* in_sizes, int n_in,
                              void* d_out, int out_size, void* d_ws, size_t ws_size,
                              hipStream_t stream) {
    const float* x = (const float*)d_in[0];       // [16,128,56,56]
    const float* proto = (const float*)d_in[1];   // [1,2000,128]
    float* out = (float*)d_out;
    float* ws = (float*)d_ws;

    if (ws_size >= WS_MID) {
        bool big = (ws_size >= WS_BIG);
        float* x2 = ws + WS_X2;
        unsigned* k1w = (unsigned*)(ws + WS_K1);
        unsigned* k2w = (unsigned*)(ws + WS_K2);
        unsigned short* pt = (unsigned short*)(ws + WS_PT);
        unsigned short* xt = (unsigned short*)(ws + WS_XT);
        float* xfT = big ? (ws + WS_XFT) : nullptr;

        pp_fused<<<dim3(50, BATCH), 256, 0, stream>>>(x, proto, xt, pt, x2, xfT);
        proto_mfma<<<1536, 256, 0, stream>>>(xt, pt, x2, k1w, k2w);
        if (big)
            fixup<0><<<(BATCH * PROT) / 4, 256, 0, stream>>>(x, xfT, proto, k1w, k2w, out);
        else
            fixup<1><<<(BATCH * PROT) / 4, 256, 0, stream>>>(x, nullptr, proto, k1w, k2w, out);
    } else {
        float* p2 = ws;
        float* x2 = ws + 2048;
        p2_kernel<<<(PROT + 255) / 256, 256, 0, stream>>>(proto, p2);
        x2_kernel<<<(BATCH * NPTS + 255) / 256, 256, 0, stream>>>(x, x2);
        dim3 grid((PROT + TP - 1) / TP, BATCH);
        proto_main<<<grid, 256, 0, stream>>>(x, proto, p2, x2, out);
    }
}

// Round 18
// 74.823 us; speedup vs baseline: 1.8920x; 1.0323x over previous
//
#include <hip/hip_runtime.h>
#include <hip/hip_bf16.h>
#include <cmath>

#define DDIM 128
#define NPTS 3136   // 56*56
#define NCHUNK 196  // NPTS/16
#define BATCH 16
#define PROT 2000
#define PPAD 2048   // 16 tiles * 128

typedef __attribute__((ext_vector_type(8))) short bf16x8;
typedef __attribute__((ext_vector_type(4))) float f32x4;
typedef __attribute__((ext_vector_type(4))) unsigned int u32x4;

// ---- workspace layout (float/u32 slot indices) ----
#define WS_X2   0                      // 50176
#define WS_K1   50176                  // 262144 (16 b x 8 piece slots x 2048; 6 used)
#define WS_K2   312320                 // 262144
#define WS_PT   574464                 // 131072 slots (= 262144 shorts, 2048x128)
#define WS_XT   705536                 // 3211264 slots (= 16*196*4096 bytes)
#define WS_XFT  3916800                // 6422528 (16*3136*128 f32)
#define WS_MID  ((size_t)3916800 * 4)
#define WS_BIG  ((size_t)10339328 * 4)

// ---------------- bf16 helpers ----------------
__device__ inline unsigned short bf16rn(float a) {
    unsigned u = __float_as_uint(a);
    unsigned r = u + 0x7FFFu + ((u >> 16) & 1u);
    return (unsigned short)(r >> 16);
}

__device__ __forceinline__ void gload_lds16(const void* g, void* l) {
    __builtin_amdgcn_global_load_lds(
        (const __attribute__((address_space(1))) void*)g,
        (__attribute__((address_space(3))) void*)l, 16, 0, 0);
}
__device__ __forceinline__ void gload_lds4(const void* g, void* l) {
    __builtin_amdgcn_global_load_lds(
        (const __attribute__((address_space(1))) void*)g,
        (__attribute__((address_space(3))) void*)l, 4, 0, 0);
}

// ---------------- fused pre-pass ----------------
// Prototype branch now stores bf16(-1024*p): the MFMA then directly accumulates
// -1024*dot, and with C-init = x2' the accumulator IS the selection key float.
__global__ __launch_bounds__(256)
void pp_fused(const float* __restrict__ x, const float* __restrict__ proto,
              unsigned short* __restrict__ xt, unsigned short* __restrict__ pt,
              float* __restrict__ x2, float* __restrict__ xfT) {
    int tid = threadIdx.x;
    if (blockIdx.x == 49) {               // prototype part: 8 blocks x 256 = 2048
        int by = blockIdx.y;
        if (by >= 8) return;
        int p = by * 256 + tid;           // 0..2047
        int ps = min(p, PROT - 1);
        const float* src = proto + (size_t)ps * DDIM;
        unsigned short* dst = pt + (size_t)p * 128;
        for (int j = 0; j < DDIM; ++j) dst[j] = bf16rn(src[j] * -1024.0f);
        return;
    }
    __shared__ float xs[DDIM][64];
    int b = blockIdx.y;
    int n0 = blockIdx.x * 64;
    {
        int r = tid >> 4, c = tid & 15;
        #pragma unroll
        for (int it = 0; it < 8; ++it) {
            int row = it * 16 + r;
            f32x4 v = *(const f32x4*)(x + ((size_t)(b * DDIM + row)) * NPTS + n0 + c * 4);
            *(f32x4*)(&xs[row][c * 4]) = v;
        }
    }
    __syncthreads();
    if (tid < 64) {
        float s = 0.f;
        #pragma unroll 8
        for (int d = 0; d < DDIM; ++d) { float v = xs[d][tid]; s = fmaf(v, v, s); }
        x2[b * NPTS + n0 + tid] = (s + 512.0f) * 512.0f;
    }
    int n = tid & 63, kk = tid >> 6;
    int nl = n & 15, ci = (n0 + n) >> 4;
    unsigned int hw[16];
    #pragma unroll
    for (int j = 0; j < 16; ++j) {
        unsigned short h0 = bf16rn(xs[kk * 32 + 2 * j][n]);
        unsigned short h1 = bf16rn(xs[kk * 32 + 2 * j + 1][n]);
        hw[j] = (unsigned)h0 | ((unsigned)h1 << 16);
    }
    char* cb = (char*)xt + ((size_t)b * NCHUNK + ci) * 4096;
    #pragma unroll
    for (int g = 0; g < 4; ++g)
        *(u32x4*)(cb + kk * 1024 + g * 256 + nl * 16) = *(u32x4*)(&hw[g * 4]);
    if (xfT) {
        float* fo = xfT + ((size_t)b * NPTS + n0 + n) * DDIM + kk * 32;
        #pragma unroll
        for (int g = 0; g < 8; ++g) {
            f32x4 v;
            v[0] = xs[kk * 32 + g * 4 + 0][n];
            v[1] = xs[kk * 32 + g * 4 + 1][n];
            v[2] = xs[kk * 32 + g * 4 + 2][n];
            v[3] = xs[kk * 32 + g * 4 + 3][n];
            *(f32x4*)(fo + g * 4) = v;
        }
    }
}

// ---------------- main MFMA kernel (r17 skeleton + key-in-acc + tree top-2) ----------------
// grid 1536 = (16 ptile x 16 b x 6 n-pieces) XCD-swizzled; block 256 = 4 waves
// = 4 psg x 32 p each. Pieces: 4x33 + 2x32 chunks. Counted-vmcnt(2), 4-buf ring.
// acc init = x2' (C-operand); pt holds -1024*p  =>  acc[rr] = key float directly.
__global__ __launch_bounds__(256, 6)
void proto_mfma(const unsigned short* __restrict__ xt,
                const unsigned short* __restrict__ pt,
                const float* __restrict__ x2,
                unsigned* __restrict__ k1w, unsigned* __restrict__ k2w) {
    // hand-placed LDS: [0,4K) x2s (<=528 used) | [4K,20K) As[4buf][4K]
    __shared__ __align__(16) char LDS[20480];
    float* x2s = (float*)LDS;
    char*  AsB = LDS + 4096;

    int lid = blockIdx.x;                      // 0..1535
    int sid = (lid & 7) * 192 + (lid >> 3);    // bijective XCD chunking (1536%8==0)
    int b = sid / 96;                          // 16 b
    int rest = sid - b * 96;
    int pbase = (rest / 6) * 128;              // 16 ptiles of 128
    int q6 = rest % 6;                         // 6 n-pieces

    int L = (q6 < 4) ? 33 : 32;                // chunks in this piece
    int start = (q6 < 4) ? q6 * 33 : 132 + (q6 - 4) * 32;

    int tid = threadIdx.x;
    int lane = tid & 63, psg = tid >> 6;       // 4 p-groups of 32p, shared n-stream
    int l15 = lane & 15, lg = lane >> 4;

    // B fragments: 2 sets x 4 named bf16x8 (32 VGPR), resident
    const unsigned short* bpa = pt + (size_t)(pbase + psg * 32 + l15) * 128 + lg * 8;
    const unsigned short* bpb = bpa + (size_t)16 * 128;
    bf16x8 Ba0 = *(const bf16x8*)(bpa);
    bf16x8 Ba1 = *(const bf16x8*)(bpa + 32);
    bf16x8 Ba2 = *(const bf16x8*)(bpa + 64);
    bf16x8 Ba3 = *(const bf16x8*)(bpa + 96);
    bf16x8 Bb0 = *(const bf16x8*)(bpb);
    bf16x8 Bb1 = *(const bf16x8*)(bpb + 32);
    bf16x8 Bb2 = *(const bf16x8*)(bpb + 64);
    bf16x8 Bb3 = *(const bf16x8*)(bpb + 96);

    const char* srcBase = (const char*)xt + ((size_t)b * NCHUNK + start) * 4096;
    const char* aread = AsB + lane * 16;       // + buf*4096 + kk*1024
    const int qOfs = start * 16;
    const int nbBase = qOfs + lg * 4;          // + chunk*16 + rr

    unsigned K1a = 0xFFFFFFFFu, K2a = 0xFFFFFFFFu;
    unsigned K1b = 0xFFFFFFFFu, K2b = 0xFFFFFFFFu;

    // ---- prologue: x2 piece slice (3 dword-DMAs, clamped; 768>=528) + chunks 0,1,2 ----
    {
        const float* xsrc = x2 + (size_t)b * NPTS + qOfs;
        #pragma unroll
        for (int r = 0; r < 3; ++r)
            gload_lds4(xsrc + min(r * 256 + psg * 64 + lane, L * 16 - 1),
                       (char*)x2s + (r * 256 + psg * 64) * 4);
    }
    #pragma unroll
    for (int r = 0; r < 3; ++r)
        gload_lds16(srcBase + (size_t)r * 4096 + psg * 1024 + (size_t)lane * 16,
                    AsB + r * 4096 + psg * 1024);

    // Tree top-2 of the 4 fresh keys, then 3-op merge into (K1,K2).
#define PMF_TOP2(ACC, NB, K1, K2)                                                   \
    {                                                                               \
        unsigned q0 = ((unsigned)(ACC)[0] << 12) | (unsigned)((NB) + 0);            \
        unsigned q1 = ((unsigned)(ACC)[1] << 12) | (unsigned)((NB) + 1);            \
        unsigned q2 = ((unsigned)(ACC)[2] << 12) | (unsigned)((NB) + 2);            \
        unsigned q3 = ((unsigned)(ACC)[3] << 12) | (unsigned)((NB) + 3);            \
        unsigned lo01 = min(q0, q1), hi01 = max(q0, q1);                            \
        unsigned lo23 = min(q2, q3), hi23 = max(q2, q3);                            \
        unsigned t1 = min(lo01, lo23);                                              \
        unsigned t2 = min(max(lo01, lo23), min(hi01, hi23));                        \
        K2 = min(min(K2, t2), max(K1, t1));                                         \
        K1 = min(K1, t1);                                                           \
    }

#define PMF_BODY(T, U)                                                              \
    {                                                                               \
        asm volatile("s_waitcnt vmcnt(2)" ::: "memory");                            \
        __builtin_amdgcn_s_barrier();                                               \
        int cln = (T) + 3;                                                          \
        cln = cln > L - 1 ? L - 1 : cln;                                            \
        gload_lds16(srcBase + (size_t)cln * 4096 + psg * 1024 + (size_t)lane * 16,  \
                    AsB + (((U) + 3) & 3) * 4096 + psg * 1024);                     \
        f32x4 xv = *(const f32x4*)&x2s[(T) * 16 + lg * 4];                          \
        const char* ar = aread + (U) * 4096;                                        \
        bf16x8 A0 = *(const bf16x8*)(ar);                                           \
        bf16x8 A1 = *(const bf16x8*)(ar + 1024);                                    \
        bf16x8 A2 = *(const bf16x8*)(ar + 2048);                                    \
        bf16x8 A3 = *(const bf16x8*)(ar + 3072);                                    \
        f32x4 accA = xv;                                                            \
        f32x4 accB = xv;                                                            \
        __builtin_amdgcn_s_setprio(1);                                              \
        accA = __builtin_amdgcn_mfma_f32_16x16x32_bf16(A0, Ba0, accA, 0, 0, 0);     \
        accB = __builtin_amdgcn_mfma_f32_16x16x32_bf16(A0, Bb0, accB, 0, 0, 0);     \
        accA = __builtin_amdgcn_mfma_f32_16x16x32_bf16(A1, Ba1, accA, 0, 0, 0);     \
        accB = __builtin_amdgcn_mfma_f32_16x16x32_bf16(A1, Bb1, accB, 0, 0, 0);     \
        accA = __builtin_amdgcn_mfma_f32_16x16x32_bf16(A2, Ba2, accA, 0, 0, 0);     \
        accB = __builtin_amdgcn_mfma_f32_16x16x32_bf16(A2, Bb2, accB, 0, 0, 0);     \
        accA = __builtin_amdgcn_mfma_f32_16x16x32_bf16(A3, Ba3, accA, 0, 0, 0);     \
        accB = __builtin_amdgcn_mfma_f32_16x16x32_bf16(A3, Bb3, accB, 0, 0, 0);     \
        __builtin_amdgcn_s_setprio(0);                                              \
        int nb = nbBase + (T) * 16;                                                 \
        PMF_TOP2(accA, nb, K1a, K2a)                                                \
        PMF_TOP2(accB, nb, K1b, K2b)                                                \
    }

    // 32 bodies in 8 unrolled groups; L==33 pieces run one extra body (32&3==0 -> buf 0).
    #pragma unroll 1
    for (int t0 = 0; t0 < 32; t0 += 4) {
        PMF_BODY(t0 + 0, 0)
        PMF_BODY(t0 + 1, 1)
        PMF_BODY(t0 + 2, 2)
        PMF_BODY(t0 + 3, 3)
    }
    if (L == 33) {
        PMF_BODY(32, 0)
    }
#undef PMF_BODY
#undef PMF_TOP2

    // ---- reduce across the 4 row-groups (lanes l, l+16, l+32, l+48) ----
    #pragma unroll
    for (int m = 16; m <= 32; m <<= 1) {
        unsigned c1a = (unsigned)__shfl_xor((int)K1a, m, 64);
        unsigned c2a = (unsigned)__shfl_xor((int)K2a, m, 64);
        unsigned wa  = max(K1a, c1a);
        K1a = min(K1a, c1a);
        K2a = min(wa, min(K2a, c2a));
        unsigned c1b = (unsigned)__shfl_xor((int)K1b, m, 64);
        unsigned c2b = (unsigned)__shfl_xor((int)K2b, m, 64);
        unsigned wb  = max(K1b, c1b);
        K1b = min(K1b, c1b);
        K2b = min(wb, min(K2b, c2b));
    }
    // each wave owns 32 distinct p -> direct global writes, no cross-wave reduce
    if (lg == 0) {
        size_t o = ((size_t)b * 8 + q6) * PPAD + pbase + psg * 32 + l15;
        k1w[o] = K1a;
        k2w[o] = K2a;
        k1w[o + 16] = K1b;
        k2w[o + 16] = K2b;
    }
}

// ---------------- exact fp32 fixup: merge 6 piece-top-2s -> 2 triplet-top-2s ----------------
// Pieces disjoint in n; within a piece a<=c. For a triplet, top1=min(a); top2 =
// min(second_min(a), min(c)) is EXACT. 4 candidates = top-2 over each ~half of n.
template<int MODE>
__global__ __launch_bounds__(256)
void fixup(const float* __restrict__ x, const float* __restrict__ xfT,
           const float* __restrict__ proto,
           const unsigned* __restrict__ k1w, const unsigned* __restrict__ k2w,
           float* __restrict__ out) {
    int tid = threadIdx.x;
    int lane = tid & 63, wv = tid >> 6;
    long long pair = (long long)blockIdx.x * 4 + wv;
    if (pair >= (long long)BATCH * PROT) return;
    int b = (int)(pair / PROT), p = (int)(pair % PROT);
    unsigned a[6], c[6];
    #pragma unroll
    for (int qq = 0; qq < 6; ++qq) {
        a[qq] = k1w[((size_t)b * 8 + qq) * PPAD + p];
        c[qq] = k2w[((size_t)b * 8 + qq) * PPAD + p];
    }
    int cand[4];
    #pragma unroll
    for (int h = 0; h < 2; ++h) {
        int o = h * 3;
        unsigned lo = min(a[o], a[o + 1]);
        unsigned hi = max(a[o], a[o + 1]);
        unsigned t1 = min(lo, a[o + 2]);
        unsigned sec = min(hi, max(lo, a[o + 2]));           // second smallest of firsts
        unsigned t2 = min(sec, min(c[o], min(c[o + 1], c[o + 2])));
        cand[h * 2]     = (int)(t1 & 0xFFFu);
        cand[h * 2 + 1] = (int)(t2 & 0xFFFu);
    }

    int d0 = lane, d1 = lane + 64;
    float pa0 = proto[(size_t)p * DDIM + d0], pa1 = proto[(size_t)p * DDIM + d1];
    float sp2 = pa0 * pa0 + pa1 * pa1;
    float f0[4], f1[4], sxp[4], sx2[4];
    #pragma unroll
    for (int cc = 0; cc < 4; ++cc) {
        int n = cand[cc];
        float v0, v1;
        if (MODE == 0) {
            const float* f = xfT + ((size_t)b * NPTS + n) * DDIM;
            v0 = f[d0]; v1 = f[d1];
        } else {
            const float* xb = x + (size_t)b * DDIM * NPTS;
            v0 = xb[(size_t)d0 * NPTS + n]; v1 = xb[(size_t)d1 * NPTS + n];
        }
        f0[cc] = v0; f1[cc] = v1;
        sxp[cc] = v0 * pa0 + v1 * pa1;
        sx2[cc] = v0 * v0 + v1 * v1;
    }
    #pragma unroll
    for (int m = 1; m < 64; m <<= 1) {
        sp2 += __shfl_xor(sp2, m, 64);
        #pragma unroll
        for (int cc = 0; cc < 4; ++cc) {
            sxp[cc] += __shfl_xor(sxp[cc], m, 64);
            sx2[cc] += __shfl_xor(sx2[cc], m, 64);
        }
    }
    float bd = 3e38f; int bn = 0x7FFFFFFF; int bc = 0;
    #pragma unroll
    for (int cc = 0; cc < 4; ++cc) {
        float d2 = fmaxf(sx2[cc] + sp2 - 2.f * sxp[cc], 0.f);
        bool w = (d2 < bd) || (d2 == bd && cand[cc] < bn);
        bd = w ? d2 : bd;
        bn = w ? cand[cc] : bn;
        bc = w ? cc : bc;
    }
    float dm = sqrtf(bd);
    float sim = logf((dm + 1.0f) / (dm + 1e-7f));
    if (lane == 0) {
        out[(size_t)b * PROT + p] = sim;
        out[(size_t)BATCH * PROT + (size_t)b * PROT + p] = dm;
    }
    float o0 = f0[0], o1 = f1[0];
    #pragma unroll
    for (int cc = 1; cc < 4; ++cc) {
        o0 = (bc == cc) ? f0[cc] : o0;
        o1 = (bc == cc) ? f1[cc] : o1;
    }
    float* fo = out + (size_t)2 * BATCH * PROT + ((size_t)b * PROT + p) * DDIM;
    fo[d0] = o0;
    fo[d1] = o1;
}

// ================= fallback fp32 path (round-1, known-good) =================
#define TP 64
#define TN 64
__global__ void p2_kernel(const float* __restrict__ proto, float* __restrict__ p2) {
    int p = blockIdx.x * blockDim.x + threadIdx.x;
    if (p >= PROT) return;
    const float4* pr = reinterpret_cast<const float4*>(proto + (size_t)p * DDIM);
    float s = 0.f;
    #pragma unroll
    for (int i = 0; i < DDIM / 4; ++i) {
        float4 v = pr[i];
        s += v.x * v.x + v.y * v.y + v.z * v.z + v.w * v.w;
    }
    p2[p] = s;
}
__global__ void x2_kernel(const float* __restrict__ x, float* __restrict__ x2) {
    int idx = blockIdx.x * blockDim.x + threadIdx.x;
    if (idx >= BATCH * NPTS) return;
    int b = idx / NPTS, n = idx - b * NPTS;
    const float* xp = x + (size_t)b * DDIM * NPTS + n;
    float s = 0.f;
    #pragma unroll 8
    for (int d = 0; d < DDIM; ++d) { float v = xp[(size_t)d * NPTS]; s += v * v; }
    x2[idx] = s;
}
__global__ __launch_bounds__(256, 2)
void proto_main(const float* __restrict__ x, const float* __restrict__ proto,
                const float* __restrict__ p2, const float* __restrict__ x2,
                float* __restrict__ out) {
    __shared__ __align__(16) float xs[DDIM][TN];
    __shared__ __align__(16) float pst[DDIM][TP];
    __shared__ float p2s[TP];
    __shared__ float x2s[TN];
    __shared__ float red_d2[16][TP];
    __shared__ int   red_n[16][TP];
    __shared__ int   bestn_s[TP];
    const int b = blockIdx.y;
    const int pbase = blockIdx.x * TP;
    const int tid = threadIdx.x;
    {
        #pragma unroll
        for (int it = 0; it < (TP * DDIM / 4) / 256; ++it) {
            int idx = it * 256 + tid;
            int p = idx / (DDIM / 4);
            int dq = idx - p * (DDIM / 4);
            int gp = min(pbase + p, PROT - 1);
            float4 v = reinterpret_cast<const float4*>(proto)[(size_t)gp * (DDIM / 4) + dq];
            pst[dq * 4 + 0][p] = v.x; pst[dq * 4 + 1][p] = v.y;
            pst[dq * 4 + 2][p] = v.z; pst[dq * 4 + 3][p] = v.w;
        }
        if (tid < TP) p2s[tid] = p2[min(pbase + tid, PROT - 1)];
    }
    const int tn = tid >> 4;
    const int tp = tid & 15;
    float best[4]; int bestn[4];
    #pragma unroll
    for (int j = 0; j < 4; ++j) { best[j] = 1e30f; bestn[j] = 0; }
    for (int n0 = 0; n0 < NPTS; n0 += TN) {
        __syncthreads();
        {
            int r = tid >> 4, c = tid & 15;
            #pragma unroll
            for (int it = 0; it < 8; ++it) {
                int row = it * 16 + r;
                float4 v = *reinterpret_cast<const float4*>(
                    x + ((size_t)(b * DDIM + row)) * NPTS + n0 + c * 4);
                *reinterpret_cast<float4*>(&xs[row][c * 4]) = v;
            }
        }
        if (tid < TN) x2s[tid] = x2[b * NPTS + n0 + tid];
        __syncthreads();
        float acc[4][4];
        #pragma unroll
        for (int i = 0; i < 4; ++i)
            #pragma unroll
            for (int j = 0; j < 4; ++j) acc[i][j] = 0.f;
        #pragma unroll 16
        for (int d = 0; d < DDIM; ++d) {
            const float4 a = *reinterpret_cast<const float4*>(&xs[d][tn * 4]);
            const float4 bv = *reinterpret_cast<const float4*>(&pst[d][tp * 4]);
            const float av[4] = {a.x, a.y, a.z, a.w};
            const float bw[4] = {bv.x, bv.y, bv.z, bv.w};
            #pragma unroll
            for (int i = 0; i < 4; ++i)
                #pragma unroll
                for (int j = 0; j < 4; ++j) acc[i][j] = fmaf(av[i], bw[j], acc[i][j]);
        }
        #pragma unroll
        for (int i = 0; i < 4; ++i) {
            float xv = x2s[tn * 4 + i];
            int n = n0 + tn * 4 + i;
            #pragma unroll
            for (int j = 0; j < 4; ++j) {
                float d2 = xv + p2s[tp * 4 + j] - 2.0f * acc[i][j];
                if (d2 < best[j]) { best[j] = d2; bestn[j] = n; }
            }
        }
    }
    #pragma unroll
    for (int j = 0; j < 4; ++j) {
        red_d2[tn][tp * 4 + j] = best[j];
        red_n[tn][tp * 4 + j] = bestn[j];
    }
    __syncthreads();
    if (tid < TP) {
        float bd = red_d2[0][tid]; int bn = red_n[0][tid];
        #pragma unroll
        for (int t = 1; t < 16; ++t) {
            float dv = red_d2[t][tid]; int nv = red_n[t][tid];
            if (dv < bd || (dv == bd && nv < bn)) { bd = dv; bn = nv; }
        }
        int gp = pbase + tid;
        if (gp < PROT) {
            float d2c = fmaxf(bd, 0.f);
            float dmin = sqrtf(d2c);
            float sim = logf((dmin + 1.0f) / (dmin + 1e-7f));
            out[(size_t)b * PROT + gp] = sim;
            out[(size_t)BATCH * PROT + (size_t)b * PROT + gp] = dmin;
        }
        bestn_s[tid] = bn;
    }
    __syncthreads();
    {
        int pl = tid >> 2, dbase = (tid & 3) * 32;
        int gp = pbase + pl;
        if (gp < PROT) {
            int n = bestn_s[pl];
            float* dst = out + (size_t)2 * BATCH * PROT + ((size_t)(b * PROT + gp)) * DDIM + dbase;
            const float* src = x + ((size_t)(b * DDIM + dbase)) * NPTS + n;
            #pragma unroll 8
            for (int d = 0; d < 32; ++d) dst[d] = src[(size_t)d * NPTS];
        }
    }
}

extern "C" void kernel_launch(void* const* d_in, const int* in_sizes, int n_in,
                              void* d_out, int out_size, void* d_ws, size_t ws_size,
                              hipStream_t stream) {
    const float* x = (const float*)d_in[0];       // [16,128,56,56]
    const float* proto = (const float*)d_in[1];   // [1,2000,128]
    float* out = (float*)d_out;
    float* ws = (float*)d_ws;

    if (ws_size >= WS_MID) {
        bool big = (ws_size >= WS_BIG);
        float* x2 = ws + WS_X2;
        unsigned* k1w = (unsigned*)(ws + WS_K1);
        unsigned* k2w = (unsigned*)(ws + WS_K2);
        unsigned short* pt = (unsigned short*)(ws + WS_PT);
        unsigned short* xt = (unsigned short*)(ws + WS_XT);
        float* xfT = big ? (ws + WS_XFT) : nullptr;

        pp_fused<<<dim3(50, BATCH), 256, 0, stream>>>(x, proto, xt, pt, x2, xfT);
        proto_mfma<<<1536, 256, 0, stream>>>(xt, pt, x2, k1w, k2w);
        if (big)
            fixup<0><<<(BATCH * PROT) / 4, 256, 0, stream>>>(x, xfT, proto, k1w, k2w, out);
        else
            fixup<1><<<(BATCH * PROT) / 4, 256, 0, stream>>>(x, nullptr, proto, k1w, k2w, out);
    } else {
        float* p2 = ws;
        float* x2 = ws + 2048;
        p2_kernel<<<(PROT + 255) / 256, 256, 0, stream>>>(proto, p2);
        x2_kernel<<<(BATCH * NPTS + 255) / 256, 256, 0, stream>>>(x, x2);
        dim3 grid((PROT + TP - 1) / TP, BATCH);
        proto_main<<<grid, 256, 0, stream>>>(x, proto, p2, x2, out);
    }
}

// Round 19
// 68.107 us; speedup vs baseline: 2.0786x; 1.0986x over previous
//
#include <hip/hip_runtime.h>
#include <hip/hip_bf16.h>
#include <cmath>

#define DDIM 128
#define NPTS 3136   // 56*56
#define NCHUNK 196  // NPTS/16
#define BATCH 16
#define PROT 2000
#define PPAD 2048   // 16 tiles * 128

typedef __attribute__((ext_vector_type(8))) short bf16x8;
typedef __attribute__((ext_vector_type(4))) float f32x4;
typedef __attribute__((ext_vector_type(4))) unsigned int u32x4;

// ---- workspace layout (float/u32 slot indices) ----
#define WS_X2   0                      // 50176
#define WS_P2   50176                  // 2048
#define WS_K1   52224                  // 262144 (16 b x 8 piece slots x 2048; 6 used)
#define WS_K2   314368                 // 262144
#define WS_PT   576512                 // 131072 slots (= 262144 shorts, 2048x128)
#define WS_XT   707584                 // 3211264 slots (= 16*196*4096 bytes)
#define WS_XFT  3918848                // 6422528 (16*3136*128 f32)
#define WS_MID  ((size_t)3918848 * 4)
#define WS_BIG  ((size_t)10341376 * 4)

// ---------------- bf16 helpers ----------------
__device__ inline unsigned short bf16rn(float a) {
    unsigned u = __float_as_uint(a);
    unsigned r = u + 0x7FFFu + ((u >> 16) & 1u);
    return (unsigned short)(r >> 16);
}

__device__ __forceinline__ void gload_lds16(const void* g, void* l) {
    __builtin_amdgcn_global_load_lds(
        (const __attribute__((address_space(1))) void*)g,
        (__attribute__((address_space(3))) void*)l, 16, 0, 0);
}
__device__ __forceinline__ void gload_lds4(const void* g, void* l) {
    __builtin_amdgcn_global_load_lds(
        (const __attribute__((address_space(1))) void*)g,
        (__attribute__((address_space(3))) void*)l, 4, 0, 0);
}

// ---------------- fused pre-pass ----------------
// Prototype branch stores bf16(-1024*p) (key-in-acc trick) AND exact p2[p].
__global__ __launch_bounds__(256)
void pp_fused(const float* __restrict__ x, const float* __restrict__ proto,
              unsigned short* __restrict__ xt, unsigned short* __restrict__ pt,
              float* __restrict__ x2, float* __restrict__ p2w,
              float* __restrict__ xfT) {
    int tid = threadIdx.x;
    if (blockIdx.x == 49) {               // prototype part: 8 blocks x 256 = 2048
        int by = blockIdx.y;
        if (by >= 8) return;
        int p = by * 256 + tid;           // 0..2047
        int ps = min(p, PROT - 1);
        const float* src = proto + (size_t)ps * DDIM;
        unsigned short* dst = pt + (size_t)p * 128;
        float s = 0.f;
        for (int j = 0; j < DDIM; ++j) {
            float v = src[j];
            s = fmaf(v, v, s);
            dst[j] = bf16rn(v * -1024.0f);
        }
        p2w[p] = s;
        return;
    }
    __shared__ float xs[DDIM][64];
    int b = blockIdx.y;
    int n0 = blockIdx.x * 64;
    {
        int r = tid >> 4, c = tid & 15;
        #pragma unroll
        for (int it = 0; it < 8; ++it) {
            int row = it * 16 + r;
            f32x4 v = *(const f32x4*)(x + ((size_t)(b * DDIM + row)) * NPTS + n0 + c * 4);
            *(f32x4*)(&xs[row][c * 4]) = v;
        }
    }
    __syncthreads();
    if (tid < 64) {
        float s = 0.f;
        #pragma unroll 8
        for (int d = 0; d < DDIM; ++d) { float v = xs[d][tid]; s = fmaf(v, v, s); }
        x2[b * NPTS + n0 + tid] = (s + 512.0f) * 512.0f;
    }
    int n = tid & 63, kk = tid >> 6;
    int nl = n & 15, ci = (n0 + n) >> 4;
    unsigned int hw[16];
    #pragma unroll
    for (int j = 0; j < 16; ++j) {
        unsigned short h0 = bf16rn(xs[kk * 32 + 2 * j][n]);
        unsigned short h1 = bf16rn(xs[kk * 32 + 2 * j + 1][n]);
        hw[j] = (unsigned)h0 | ((unsigned)h1 << 16);
    }
    char* cb = (char*)xt + ((size_t)b * NCHUNK + ci) * 4096;
    #pragma unroll
    for (int g = 0; g < 4; ++g)
        *(u32x4*)(cb + kk * 1024 + g * 256 + nl * 16) = *(u32x4*)(&hw[g * 4]);
    if (xfT) {
        float* fo = xfT + ((size_t)b * NPTS + n0 + n) * DDIM + kk * 32;
        #pragma unroll
        for (int g = 0; g < 8; ++g) {
            f32x4 v;
            v[0] = xs[kk * 32 + g * 4 + 0][n];
            v[1] = xs[kk * 32 + g * 4 + 1][n];
            v[2] = xs[kk * 32 + g * 4 + 2][n];
            v[3] = xs[kk * 32 + g * 4 + 3][n];
            *(f32x4*)(fo + g * 4) = v;
        }
    }
}

// ---------------- main MFMA kernel (r18, proven: key-in-acc + tree top-2) ----------------
// grid 1536 = (16 ptile x 16 b x 6 n-pieces) XCD-swizzled; block 256 = 4 waves
// = 4 psg x 32 p each. Pieces: 4x33 + 2x32 chunks. Counted-vmcnt(2), 4-buf ring.
__global__ __launch_bounds__(256, 6)
void proto_mfma(const unsigned short* __restrict__ xt,
                const unsigned short* __restrict__ pt,
                const float* __restrict__ x2,
                unsigned* __restrict__ k1w, unsigned* __restrict__ k2w) {
    // hand-placed LDS: [0,4K) x2s (<=528 used) | [4K,20K) As[4buf][4K]
    __shared__ __align__(16) char LDS[20480];
    float* x2s = (float*)LDS;
    char*  AsB = LDS + 4096;

    int lid = blockIdx.x;                      // 0..1535
    int sid = (lid & 7) * 192 + (lid >> 3);    // bijective XCD chunking (1536%8==0)
    int b = sid / 96;                          // 16 b
    int rest = sid - b * 96;
    int pbase = (rest / 6) * 128;              // 16 ptiles of 128
    int q6 = rest % 6;                         // 6 n-pieces

    int L = (q6 < 4) ? 33 : 32;                // chunks in this piece
    int start = (q6 < 4) ? q6 * 33 : 132 + (q6 - 4) * 32;

    int tid = threadIdx.x;
    int lane = tid & 63, psg = tid >> 6;       // 4 p-groups of 32p, shared n-stream
    int l15 = lane & 15, lg = lane >> 4;

    // B fragments: 2 sets x 4 named bf16x8 (32 VGPR), resident
    const unsigned short* bpa = pt + (size_t)(pbase + psg * 32 + l15) * 128 + lg * 8;
    const unsigned short* bpb = bpa + (size_t)16 * 128;
    bf16x8 Ba0 = *(const bf16x8*)(bpa);
    bf16x8 Ba1 = *(const bf16x8*)(bpa + 32);
    bf16x8 Ba2 = *(const bf16x8*)(bpa + 64);
    bf16x8 Ba3 = *(const bf16x8*)(bpa + 96);
    bf16x8 Bb0 = *(const bf16x8*)(bpb);
    bf16x8 Bb1 = *(const bf16x8*)(bpb + 32);
    bf16x8 Bb2 = *(const bf16x8*)(bpb + 64);
    bf16x8 Bb3 = *(const bf16x8*)(bpb + 96);

    const char* srcBase = (const char*)xt + ((size_t)b * NCHUNK + start) * 4096;
    const char* aread = AsB + lane * 16;       // + buf*4096 + kk*1024
    const int qOfs = start * 16;
    const int nbBase = qOfs + lg * 4;          // + chunk*16 + rr

    unsigned K1a = 0xFFFFFFFFu, K2a = 0xFFFFFFFFu;
    unsigned K1b = 0xFFFFFFFFu, K2b = 0xFFFFFFFFu;

    // ---- prologue: x2 piece slice (3 dword-DMAs, clamped; 768>=528) + chunks 0,1,2 ----
    {
        const float* xsrc = x2 + (size_t)b * NPTS + qOfs;
        #pragma unroll
        for (int r = 0; r < 3; ++r)
            gload_lds4(xsrc + min(r * 256 + psg * 64 + lane, L * 16 - 1),
                       (char*)x2s + (r * 256 + psg * 64) * 4);
    }
    #pragma unroll
    for (int r = 0; r < 3; ++r)
        gload_lds16(srcBase + (size_t)r * 4096 + psg * 1024 + (size_t)lane * 16,
                    AsB + r * 4096 + psg * 1024);

    // Tree top-2 of the 4 fresh keys, then 3-op merge into (K1,K2).
#define PMF_TOP2(ACC, NB, K1, K2)                                                   \
    {                                                                               \
        unsigned q0 = ((unsigned)(ACC)[0] << 12) | (unsigned)((NB) + 0);            \
        unsigned q1 = ((unsigned)(ACC)[1] << 12) | (unsigned)((NB) + 1);            \
        unsigned q2 = ((unsigned)(ACC)[2] << 12) | (unsigned)((NB) + 2);            \
        unsigned q3 = ((unsigned)(ACC)[3] << 12) | (unsigned)((NB) + 3);            \
        unsigned lo01 = min(q0, q1), hi01 = max(q0, q1);                            \
        unsigned lo23 = min(q2, q3), hi23 = max(q2, q3);                            \
        unsigned t1 = min(lo01, lo23);                                              \
        unsigned t2 = min(max(lo01, lo23), min(hi01, hi23));                        \
        K2 = min(min(K2, t2), max(K1, t1));                                         \
        K1 = min(K1, t1);                                                           \
    }

#define PMF_BODY(T, U)                                                              \
    {                                                                               \
        asm volatile("s_waitcnt vmcnt(2)" ::: "memory");                            \
        __builtin_amdgcn_s_barrier();                                               \
        int cln = (T) + 3;                                                          \
        cln = cln > L - 1 ? L - 1 : cln;                                            \
        gload_lds16(srcBase + (size_t)cln * 4096 + psg * 1024 + (size_t)lane * 16,  \
                    AsB + (((U) + 3) & 3) * 4096 + psg * 1024);                     \
        f32x4 xv = *(const f32x4*)&x2s[(T) * 16 + lg * 4];                          \
        const char* ar = aread + (U) * 4096;                                        \
        bf16x8 A0 = *(const bf16x8*)(ar);                                           \
        bf16x8 A1 = *(const bf16x8*)(ar + 1024);                                    \
        bf16x8 A2 = *(const bf16x8*)(ar + 2048);                                    \
        bf16x8 A3 = *(const bf16x8*)(ar + 3072);                                    \
        f32x4 accA = xv;                                                            \
        f32x4 accB = xv;                                                            \
        __builtin_amdgcn_s_setprio(1);                                              \
        accA = __builtin_amdgcn_mfma_f32_16x16x32_bf16(A0, Ba0, accA, 0, 0, 0);     \
        accB = __builtin_amdgcn_mfma_f32_16x16x32_bf16(A0, Bb0, accB, 0, 0, 0);     \
        accA = __builtin_amdgcn_mfma_f32_16x16x32_bf16(A1, Ba1, accA, 0, 0, 0);     \
        accB = __builtin_amdgcn_mfma_f32_16x16x32_bf16(A1, Bb1, accB, 0, 0, 0);     \
        accA = __builtin_amdgcn_mfma_f32_16x16x32_bf16(A2, Ba2, accA, 0, 0, 0);     \
        accB = __builtin_amdgcn_mfma_f32_16x16x32_bf16(A2, Bb2, accB, 0, 0, 0);     \
        accA = __builtin_amdgcn_mfma_f32_16x16x32_bf16(A3, Ba3, accA, 0, 0, 0);     \
        accB = __builtin_amdgcn_mfma_f32_16x16x32_bf16(A3, Bb3, accB, 0, 0, 0);     \
        __builtin_amdgcn_s_setprio(0);                                              \
        int nb = nbBase + (T) * 16;                                                 \
        PMF_TOP2(accA, nb, K1a, K2a)                                                \
        PMF_TOP2(accB, nb, K1b, K2b)                                                \
    }

    // 32 bodies in 8 unrolled groups; L==33 pieces run one extra body (32&3==0 -> buf 0).
    #pragma unroll 1
    for (int t0 = 0; t0 < 32; t0 += 4) {
        PMF_BODY(t0 + 0, 0)
        PMF_BODY(t0 + 1, 1)
        PMF_BODY(t0 + 2, 2)
        PMF_BODY(t0 + 3, 3)
    }
    if (L == 33) {
        PMF_BODY(32, 0)
    }
#undef PMF_BODY
#undef PMF_TOP2

    // ---- reduce across the 4 row-groups (lanes l, l+16, l+32, l+48) ----
    #pragma unroll
    for (int m = 16; m <= 32; m <<= 1) {
        unsigned c1a = (unsigned)__shfl_xor((int)K1a, m, 64);
        unsigned c2a = (unsigned)__shfl_xor((int)K2a, m, 64);
        unsigned wa  = max(K1a, c1a);
        K1a = min(K1a, c1a);
        K2a = min(wa, min(K2a, c2a));
        unsigned c1b = (unsigned)__shfl_xor((int)K1b, m, 64);
        unsigned c2b = (unsigned)__shfl_xor((int)K2b, m, 64);
        unsigned wb  = max(K1b, c1b);
        K1b = min(K1b, c1b);
        K2b = min(wb, min(K2b, c2b));
    }
    // each wave owns 32 distinct p -> direct global writes, no cross-wave reduce
    if (lg == 0) {
        size_t o = ((size_t)b * 8 + q6) * PPAD + pbase + psg * 32 + l15;
        k1w[o] = K1a;
        k2w[o] = K2a;
        k1w[o + 16] = K1b;
        k2w[o + 16] = K2b;
    }
}

// ---------------- exact fp32 fixup: 4 candidates, dot-only reduction ----------------
// sx2 and sp2 come precomputed (x2' = 512*(x2+512) in ws; p2 from pp_fused), so only
// the 4 sxp dot-chains need the 6-stage butterfly (24 ops vs 108). d2 keeps the
// reference x2+p2-2xp structure.
template<int MODE>
__global__ __launch_bounds__(256)
void fixup(const float* __restrict__ x, const float* __restrict__ xfT,
           const float* __restrict__ proto,
           const float* __restrict__ x2w, const float* __restrict__ p2w,
           const unsigned* __restrict__ k1w, const unsigned* __restrict__ k2w,
           float* __restrict__ out) {
    int tid = threadIdx.x;
    int lane = tid & 63, wv = tid >> 6;
    long long pair = (long long)blockIdx.x * 4 + wv;
    if (pair >= (long long)BATCH * PROT) return;
    int b = (int)(pair / PROT), p = (int)(pair % PROT);
    unsigned a[6], c[6];
    #pragma unroll
    for (int qq = 0; qq < 6; ++qq) {
        a[qq] = k1w[((size_t)b * 8 + qq) * PPAD + p];
        c[qq] = k2w[((size_t)b * 8 + qq) * PPAD + p];
    }
    int cand[4];
    #pragma unroll
    for (int h = 0; h < 2; ++h) {
        int o = h * 3;
        unsigned lo = min(a[o], a[o + 1]);
        unsigned hi = max(a[o], a[o + 1]);
        unsigned t1 = min(lo, a[o + 2]);
        unsigned sec = min(hi, max(lo, a[o + 2]));           // second smallest of firsts
        unsigned t2 = min(sec, min(c[o], min(c[o + 1], c[o + 2])));
        cand[h * 2]     = (int)(t1 & 0xFFFu);
        cand[h * 2 + 1] = (int)(t2 & 0xFFFu);
    }

    int d0 = lane, d1 = lane + 64;
    float pa0 = proto[(size_t)p * DDIM + d0], pa1 = proto[(size_t)p * DDIM + d1];
    float p2v = p2w[p];
    float f0[4], f1[4], sxp[4], x2c[4];
    #pragma unroll
    for (int cc = 0; cc < 4; ++cc) {
        int n = cand[cc];
        float v0, v1;
        if (MODE == 0) {
            const float* f = xfT + ((size_t)b * NPTS + n) * DDIM;
            v0 = f[d0]; v1 = f[d1];
        } else {
            const float* xb = x + (size_t)b * DDIM * NPTS;
            v0 = xb[(size_t)d0 * NPTS + n]; v1 = xb[(size_t)d1 * NPTS + n];
        }
        f0[cc] = v0; f1[cc] = v1;
        sxp[cc] = v0 * pa0 + v1 * pa1;
        x2c[cc] = x2w[(size_t)b * NPTS + n] * 0.001953125f - 512.0f;  // exact unbias
    }
    #pragma unroll
    for (int m = 1; m < 64; m <<= 1) {
        #pragma unroll
        for (int cc = 0; cc < 4; ++cc)
            sxp[cc] += __shfl_xor(sxp[cc], m, 64);
    }
    float bd = 3e38f; int bn = 0x7FFFFFFF; int bc = 0;
    #pragma unroll
    for (int cc = 0; cc < 4; ++cc) {
        float d2 = fmaxf(x2c[cc] + p2v - 2.f * sxp[cc], 0.f);
        bool w = (d2 < bd) || (d2 == bd && cand[cc] < bn);
        bd = w ? d2 : bd;
        bn = w ? cand[cc] : bn;
        bc = w ? cc : bc;
    }
    float dm = sqrtf(bd);
    float sim = logf((dm + 1.0f) / (dm + 1e-7f));
    if (lane == 0) {
        out[(size_t)b * PROT + p] = sim;
        out[(size_t)BATCH * PROT + (size_t)b * PROT + p] = dm;
    }
    float o0 = f0[0], o1 = f1[0];
    #pragma unroll
    for (int cc = 1; cc < 4; ++cc) {
        o0 = (bc == cc) ? f0[cc] : o0;
        o1 = (bc == cc) ? f1[cc] : o1;
    }
    float* fo = out + (size_t)2 * BATCH * PROT + ((size_t)b * PROT + p) * DDIM;
    fo[d0] = o0;
    fo[d1] = o1;
}

// ================= fallback fp32 path (round-1, known-good) =================
#define TP 64
#define TN 64
__global__ void p2_kernel(const float* __restrict__ proto, float* __restrict__ p2) {
    int p = blockIdx.x * blockDim.x + threadIdx.x;
    if (p >= PROT) return;
    const float4* pr = reinterpret_cast<const float4*>(proto + (size_t)p * DDIM);
    float s = 0.f;
    #pragma unroll
    for (int i = 0; i < DDIM / 4; ++i) {
        float4 v = pr[i];
        s += v.x * v.x + v.y * v.y + v.z * v.z + v.w * v.w;
    }
    p2[p] = s;
}
__global__ void x2_kernel(const float* __restrict__ x, float* __restrict__ x2) {
    int idx = blockIdx.x * blockDim.x + threadIdx.x;
    if (idx >= BATCH * NPTS) return;
    int b = idx / NPTS, n = idx - b * NPTS;
    const float* xp = x + (size_t)b * DDIM * NPTS + n;
    float s = 0.f;
    #pragma unroll 8
    for (int d = 0; d < DDIM; ++d) { float v = xp[(size_t)d * NPTS]; s += v * v; }
    x2[idx] = s;
}
__global__ __launch_bounds__(256, 2)
void proto_main(const float* __restrict__ x, const float* __restrict__ proto,
                const float* __restrict__ p2, const float* __restrict__ x2,
                float* __restrict__ out) {
    __shared__ __align__(16) float xs[DDIM][TN];
    __shared__ __align__(16) float pst[DDIM][TP];
    __shared__ float p2s[TP];
    __shared__ float x2s[TN];
    __shared__ float red_d2[16][TP];
    __shared__ int   red_n[16][TP];
    __shared__ int   bestn_s[TP];
    const int b = blockIdx.y;
    const int pbase = blockIdx.x * TP;
    const int tid = threadIdx.x;
    {
        #pragma unroll
        for (int it = 0; it < (TP * DDIM / 4) / 256; ++it) {
            int idx = it * 256 + tid;
            int p = idx / (DDIM / 4);
            int dq = idx - p * (DDIM / 4);
            int gp = min(pbase + p, PROT - 1);
            float4 v = reinterpret_cast<const float4*>(proto)[(size_t)gp * (DDIM / 4) + dq];
            pst[dq * 4 + 0][p] = v.x; pst[dq * 4 + 1][p] = v.y;
            pst[dq * 4 + 2][p] = v.z; pst[dq * 4 + 3][p] = v.w;
        }
        if (tid < TP) p2s[tid] = p2[min(pbase + tid, PROT - 1)];
    }
    const int tn = tid >> 4;
    const int tp = tid & 15;
    float best[4]; int bestn[4];
    #pragma unroll
    for (int j = 0; j < 4; ++j) { best[j] = 1e30f; bestn[j] = 0; }
    for (int n0 = 0; n0 < NPTS; n0 += TN) {
        __syncthreads();
        {
            int r = tid >> 4, c = tid & 15;
            #pragma unroll
            for (int it = 0; it < 8; ++it) {
                int row = it * 16 + r;
                float4 v = *reinterpret_cast<const float4*>(
                    x + ((size_t)(b * DDIM + row)) * NPTS + n0 + c * 4);
                *reinterpret_cast<float4*>(&xs[row][c * 4]) = v;
            }
        }
        if (tid < TN) x2s[tid] = x2[b * NPTS + n0 + tid];
        __syncthreads();
        float acc[4][4];
        #pragma unroll
        for (int i = 0; i < 4; ++i)
            #pragma unroll
            for (int j = 0; j < 4; ++j) acc[i][j] = 0.f;
        #pragma unroll 16
        for (int d = 0; d < DDIM; ++d) {
            const float4 a = *reinterpret_cast<const float4*>(&xs[d][tn * 4]);
            const float4 bv = *reinterpret_cast<const float4*>(&pst[d][tp * 4]);
            const float av[4] = {a.x, a.y, a.z, a.w};
            const float bw[4] = {bv.x, bv.y, bv.z, bv.w};
            #pragma unroll
            for (int i = 0; i < 4; ++i)
                #pragma unroll
                for (int j = 0; j < 4; ++j) acc[i][j] = fmaf(av[i], bw[j], acc[i][j]);
        }
        #pragma unroll
        for (int i = 0; i < 4; ++i) {
            float xv = x2s[tn * 4 + i];
            int n = n0 + tn * 4 + i;
            #pragma unroll
            for (int j = 0; j < 4; ++j) {
                float d2 = xv + p2s[tp * 4 + j] - 2.0f * acc[i][j];
                if (d2 < best[j]) { best[j] = d2; bestn[j] = n; }
            }
        }
    }
    #pragma unroll
    for (int j = 0; j < 4; ++j) {
        red_d2[tn][tp * 4 + j] = best[j];
        red_n[tn][tp * 4 + j] = bestn[j];
    }
    __syncthreads();
    if (tid < TP) {
        float bd = red_d2[0][tid]; int bn = red_n[0][tid];
        #pragma unroll
        for (int t = 1; t < 16; ++t) {
            float dv = red_d2[t][tid]; int nv = red_n[t][tid];
            if (dv < bd || (dv == bd && nv < bn)) { bd = dv; bn = nv; }
        }
        int gp = pbase + tid;
        if (gp < PROT) {
            float d2c = fmaxf(bd, 0.f);
            float dmin = sqrtf(d2c);
            float sim = logf((dmin + 1.0f) / (dmin + 1e-7f));
            out[(size_t)b * PROT + gp] = sim;
            out[(size_t)BATCH * PROT + (size_t)b * PROT + gp] = dmin;
        }
        bestn_s[tid] = bn;
    }
    __syncthreads();
    {
        int pl = tid >> 2, dbase = (tid & 3) * 32;
        int gp = pbase + pl;
        if (gp < PROT) {
            int n = bestn_s[pl];
            float* dst = out + (size_t)2 * BATCH * PROT + ((size_t)(b * PROT + gp)) * DDIM + dbase;
            const float* src = x + ((size_t)(b * DDIM + dbase)) * NPTS + n;
            #pragma unroll 8
            for (int d = 0; d < 32; ++d) dst[d] = src[(size_t)d * NPTS];
        }
    }
}

extern "C" void kernel_launch(void* const* d_in, const int* in_sizes, int n_in,
                              void* d_out, int out_size, void* d_ws, size_t ws_size,
                              hipStream_t stream) {
    const float* x = (const float*)d_in[0];       // [16,128,56,56]
    const float* proto = (const float*)d_in[1];   // [1,2000,128]
    float* out = (float*)d_out;
    float* ws = (float*)d_ws;

    if (ws_size >= WS_MID) {
        bool big = (ws_size >= WS_BIG);
        float* x2 = ws + WS_X2;
        float* p2w = ws + WS_P2;
        unsigned* k1w = (unsigned*)(ws + WS_K1);
        unsigned* k2w = (unsigned*)(ws + WS_K2);
        unsigned short* pt = (unsigned short*)(ws + WS_PT);
        unsigned short* xt = (unsigned short*)(ws + WS_XT);
        float* xfT = big ? (ws + WS_XFT) : nullptr;

        pp_fused<<<dim3(50, BATCH), 256, 0, stream>>>(x, proto, xt, pt, x2, p2w, xfT);
        proto_mfma<<<1536, 256, 0, stream>>>(xt, pt, x2, k1w, k2w);
        if (big)
            fixup<0><<<(BATCH * PROT) / 4, 256, 0, stream>>>(x, xfT, proto, x2, p2w, k1w, k2w, out);
        else
            fixup<1><<<(BATCH * PROT) / 4, 256, 0, stream>>>(x, nullptr, proto, x2, p2w, k1w, k2w, out);
    } else {
        float* p2 = ws;
        float* x2 = ws + 2048;
        p2_kernel<<<(PROT + 255) / 256, 256, 0, stream>>>(proto, p2);
        x2_kernel<<<(BATCH * NPTS + 255) / 256, 256, 0, stream>>>(x, x2);
        dim3 grid((PROT + TP - 1) / TP, BATCH);
        proto_main<<<grid, 256, 0, stream>>>(x, proto, p2, x2, out);
    }
}